// Round 1
// baseline (2628.487 us; speedup 1.0000x reference)
//
#include <hip/hip_runtime.h>
#include <math.h>

#define DIV_UP(a,b) (((a)+(b)-1)/(b))

// ---------- float atomic max via int ordering trick ----------
// init to -inf. For v>=0 use signed-int max; for v<0 use unsigned-int min.
// Once any non-negative lands, negatives can never win (uint(pos) < uint(neg)).
__device__ inline void atomicMaxF(float* addr, float val) {
    if (val >= 0.0f) {
        atomicMax((int*)addr, __float_as_int(val));
    } else {
        atomicMin((unsigned int*)addr, __float_as_uint(val));
    }
}

__global__ void k_fill(float* p, float v, int n) {
    int i = blockIdx.x * blockDim.x + threadIdx.x;
    if (i < n) p[i] = v;
}

__global__ void k_deg_count(const int* __restrict__ dst, float* deg, int E) {
    int i = blockIdx.x * blockDim.x + threadIdx.x;
    if (i < E) atomicAdd(&deg[dst[i]], 1.0f);
}

__global__ void k_dinv(const float* __restrict__ deg, float* __restrict__ dinv, int n) {
    int i = blockIdx.x * blockDim.x + threadIdx.x;
    if (i < n) dinv[i] = rsqrtf(deg[i]);
}

// out[i,f] = dinv[i]^2 * H[i,f] (+ bias[f])  — full init of the agg buffer.
__global__ void k_selfinit(const float* __restrict__ H, const float* __restrict__ dinv,
                           const float* __restrict__ bias, float* __restrict__ out,
                           int M, int F) {
    int f4cnt = F >> 2;
    int idx = blockIdx.x * blockDim.x + threadIdx.x;
    if (idx >= M * f4cnt) return;
    int row = idx / f4cnt;
    int f = (idx % f4cnt) << 2;
    float s = dinv[row];
    s *= s;
    float4 v = *(const float4*)&H[(size_t)row * F + f];
    float4 o;
    o.x = s * v.x; o.y = s * v.y; o.z = s * v.z; o.w = s * v.w;
    if (bias) { o.x += bias[f]; o.y += bias[f + 1]; o.z += bias[f + 2]; o.w += bias[f + 3]; }
    *(float4*)&out[(size_t)row * F + f] = o;
}

// Per edge: out[dst] += dinv[src]*dinv[dst] * H[src].  F/4 lanes per edge, float4 gather.
template <int F>
__global__ __launch_bounds__(256) void k_scatter(const float* __restrict__ H,
                                                 const int* __restrict__ src,
                                                 const int* __restrict__ dst,
                                                 const float* __restrict__ dinv,
                                                 float* __restrict__ out, int E) {
    const int LPE = F / 4;            // lanes per edge
    const int EPB = 256 / LPE;        // edges per block
    int tid = threadIdx.x;
    int e = blockIdx.x * EPB + tid / LPE;
    if (e >= E) return;
    int lane = tid % LPE;
    int s = src[e], d = dst[e];
    float nrm = dinv[s] * dinv[d];
    float4 v = *(const float4*)&H[(size_t)s * F + (lane << 2)];
    float* o = &out[(size_t)d * F + (lane << 2)];
    atomicAdd(o + 0, nrm * v.x);
    atomicAdd(o + 1, nrm * v.y);
    atomicAdd(o + 2, nrm * v.z);
    atomicAdd(o + 3, nrm * v.w);
}

// fp32 GEMM: C[M,NC] = act(A[M,K] @ B[K,NC] + bias). BM=BN=64, BK=16, 256 thr, 4x4 microtile.
__global__ __launch_bounds__(256) void k_gemm(const float* __restrict__ A,
                                              const float* __restrict__ B,
                                              const float* __restrict__ bias,
                                              float* __restrict__ C,
                                              int M, int K, int NC, int act) {
    __shared__ float As[16][68];  // transposed A tile; +4 pad keeps 16B align, <=2-way banks
    __shared__ float Bs[16][64];
    int tid = threadIdx.x;
    int row0 = blockIdx.y * 64;
    int col0 = blockIdx.x * 64;
    int a_row = tid >> 2;             // 0..63
    int a_k = (tid & 3) << 2;         // 0,4,8,12
    int b_k = tid >> 4;               // 0..15
    int b_n = (tid & 15) << 2;        // 0..60
    int tx = tid & 15, ty = tid >> 4; // microtile coords
    float acc[4][4] = {{0.f}};

    for (int k0 = 0; k0 < K; k0 += 16) {
        float4 av = make_float4(0.f, 0.f, 0.f, 0.f);
        int gr = row0 + a_row;
        if (gr < M) av = *(const float4*)&A[(size_t)gr * K + k0 + a_k];
        As[a_k + 0][a_row] = av.x;
        As[a_k + 1][a_row] = av.y;
        As[a_k + 2][a_row] = av.z;
        As[a_k + 3][a_row] = av.w;
        *(float4*)&Bs[b_k][b_n] = *(const float4*)&B[(size_t)(k0 + b_k) * NC + col0 + b_n];
        __syncthreads();
#pragma unroll
        for (int kk = 0; kk < 16; ++kk) {
            float4 a = *(const float4*)&As[kk][ty << 2];
            float4 b = *(const float4*)&Bs[kk][tx << 2];
            acc[0][0] += a.x * b.x; acc[0][1] += a.x * b.y; acc[0][2] += a.x * b.z; acc[0][3] += a.x * b.w;
            acc[1][0] += a.y * b.x; acc[1][1] += a.y * b.y; acc[1][2] += a.y * b.z; acc[1][3] += a.y * b.w;
            acc[2][0] += a.z * b.x; acc[2][1] += a.z * b.y; acc[2][2] += a.z * b.z; acc[2][3] += a.z * b.w;
            acc[3][0] += a.w * b.x; acc[3][1] += a.w * b.y; acc[3][2] += a.w * b.z; acc[3][3] += a.w * b.w;
        }
        __syncthreads();
    }

#pragma unroll
    for (int i = 0; i < 4; ++i) {
        int r = row0 + (ty << 2) + i;
        if (r >= M) continue;
        int c0 = col0 + (tx << 2);
        float4 o;
        float* pa = acc[i];
        o.x = pa[0]; o.y = pa[1]; o.z = pa[2]; o.w = pa[3];
        if (bias) { o.x += bias[c0]; o.y += bias[c0 + 1]; o.z += bias[c0 + 2]; o.w += bias[c0 + 3]; }
        if (act) {
            o.x = (o.x >= 0.f) ? o.x : 0.01f * o.x;
            o.y = (o.y >= 0.f) ? o.y : 0.01f * o.y;
            o.z = (o.z >= 0.f) ? o.z : 0.01f * o.z;
            o.w = (o.w >= 0.f) ? o.w : 0.01f * o.w;
        }
        *(float4*)&C[(size_t)r * NC + c0] = o;
    }
}

// narrow GEMM NC=32: one thread per (row, col), W staged in LDS (K<=128).
__global__ __launch_bounds__(256) void k_gemm_n32(const float* __restrict__ A,
                                                  const float* __restrict__ W,
                                                  const float* __restrict__ bias,
                                                  float* __restrict__ C, int M, int K) {
    __shared__ float Ws[128 * 32];
    int tid = threadIdx.x;
    for (int i = tid; i < K * 32; i += 256) Ws[i] = W[i];
    __syncthreads();
    int row = blockIdx.x * 8 + (tid >> 5);
    int col = tid & 31;
    if (row >= M) return;
    float acc = bias[col];
    const float* a = &A[(size_t)row * K];
    for (int k = 0; k < K; ++k) acc = fmaf(a[k], Ws[k * 32 + col], acc);
    C[(size_t)row * 32 + col] = acc;
}

// z = Z4[M,32] @ W5[32,10] + b5, fused with segment_max into out[G,10].
__global__ __launch_bounds__(320) void k_z_segmax(const float* __restrict__ Z,
                                                  const float* __restrict__ W,
                                                  const float* __restrict__ bias,
                                                  const int* __restrict__ batch,
                                                  float* __restrict__ out, int M) {
    __shared__ float Ws[320];
    __shared__ float bs[10];
    int tid = threadIdx.x;
    if (tid < 320) Ws[tid] = W[tid];
    if (tid < 10) bs[tid] = bias[tid];
    __syncthreads();
    int row = blockIdx.x * 32 + tid / 10;
    int col = tid % 10;
    if (row >= M) return;
    float acc = bs[col];
    const float* a = &Z[(size_t)row * 32];
#pragma unroll
    for (int k = 0; k < 32; ++k) acc = fmaf(a[k], Ws[k * 10 + col], acc);
    atomicMaxF(&out[(size_t)batch[row] * 10 + col], acc);
}

// segment_max of H[M,F] by batch into out[G,F] (out pre-filled with -inf).
__global__ void k_segmax(const float* __restrict__ H, const int* __restrict__ batch,
                         float* __restrict__ out, int M, int F) {
    long long idx = (long long)blockIdx.x * blockDim.x + threadIdx.x;
    if (idx >= (long long)M * F) return;
    int row = (int)(idx / F);
    int f = (int)(idx % F);
    atomicMaxF(&out[(size_t)batch[row] * F + f], H[idx]);
}

extern "C" void kernel_launch(void* const* d_in, const int* in_sizes, int n_in,
                              void* d_out, int out_size, void* d_ws, size_t ws_size,
                              hipStream_t stream) {
    const float* x  = (const float*)d_in[0];
    const int* ei   = (const int*)d_in[1];
    const int* batch= (const int*)d_in[2];
    const float* W1 = (const float*)d_in[3];
    const float* b1 = (const float*)d_in[4];
    const float* W2 = (const float*)d_in[5];
    const float* b2 = (const float*)d_in[6];
    const float* W3 = (const float*)d_in[7];
    const float* b3 = (const float*)d_in[8];
    const float* W4 = (const float*)d_in[9];
    const float* b4 = (const float*)d_in[10];
    const float* W5 = (const float*)d_in[11];
    const float* b5 = (const float*)d_in[12];

    const int N  = in_sizes[2];           // 50000
    const int F  = in_sizes[0] / N;       // 128
    const int E  = in_sizes[1] / 2;       // 400000
    const int C1 = in_sizes[4];           // 512
    const int C2 = in_sizes[6];           // 256
    const int C3 = in_sizes[8];           // 128
    const int C5 = in_sizes[12];          // 10
    const int G  = out_size / (C2 + C5);  // 512

    const int* srcp = ei;
    const int* dstp = ei + E;

    // ---- workspace layout (fp32), aliased where lifetimes permit ----
    float* ws   = (float*)d_ws;
    float* deg  = ws;                      ws += N;
    float* dinv = ws;                      ws += N;
    float* aggx = ws;                      ws += (size_t)N * F;    // later reused as z3
    float* h1   = ws;                      ws += (size_t)N * C1;   // later: h2 (first N*C2), z4 (next N*32)
    float* t2   = ws;                      ws += (size_t)N * C2;
    float* h2 = h1;
    float* z3 = aggx;
    float* z4 = h1 + (size_t)N * C2;

    float* out     = (float*)d_out;
    float* out_emb = out + (size_t)G * C5;

    // outputs start at -inf (segment_max identity; matches JAX empty-segment semantics)
    k_fill<<<DIV_UP(out_size, 256), 256, 0, stream>>>(out, -INFINITY, out_size);

    // degrees (self-loop contributes 1) and dinv
    k_fill<<<DIV_UP(N, 256), 256, 0, stream>>>(deg, 1.0f, N);
    k_deg_count<<<DIV_UP(E, 256), 256, 0, stream>>>(dstp, deg, E);
    k_dinv<<<DIV_UP(N, 256), 256, 0, stream>>>(deg, dinv, N);

    // ---- layer 1: aggregate x (128-dim), then GEMM+bias+leakyrelu ----
    k_selfinit<<<DIV_UP(N * (F / 4), 256), 256, 0, stream>>>(x, dinv, nullptr, aggx, N, F);
    k_scatter<128><<<DIV_UP(E, 8), 256, 0, stream>>>(x, srcp, dstp, dinv, aggx, E);
    dim3 g1(C1 / 64, DIV_UP(N, 64));
    k_gemm<<<g1, 256, 0, stream>>>(aggx, W1, b1, h1, N, F, C1, 1);

    // ---- layer 2: GEMM first (256-dim), then aggregate + bias ----
    dim3 g2(C2 / 64, DIV_UP(N, 64));
    k_gemm<<<g2, 256, 0, stream>>>(h1, W2, nullptr, t2, N, C1, C2, 0);
    k_selfinit<<<DIV_UP(N * (C2 / 4), 256), 256, 0, stream>>>(t2, dinv, b2, h2, N, C2);
    k_scatter<256><<<DIV_UP(E, 4), 256, 0, stream>>>(t2, srcp, dstp, dinv, h2, E);

    // ---- embs = segment_max(h2) ----
    k_segmax<<<DIV_UP(N * C2, 256), 256, 0, stream>>>(h2, batch, out_emb, N, C2);

    // ---- MLP head + segment_max ----
    dim3 g3(C3 / 64, DIV_UP(N, 64));
    k_gemm<<<g3, 256, 0, stream>>>(h2, W3, b3, z3, N, C2, C3, 0);
    k_gemm_n32<<<DIV_UP(N, 8), 256, 0, stream>>>(z3, W4, b4, z4, N, C3);
    k_z_segmax<<<DIV_UP(N, 32), 320, 0, stream>>>(z4, W5, b5, batch, out, N);
}

// Round 2
// 809.156 us; speedup vs baseline: 3.2484x; 3.2484x over previous
//
#include <hip/hip_runtime.h>
#include <math.h>

#define DIV_UP(a,b) (((a)+(b)-1)/(b))

__global__ void k_zero_i(int* p, int n) {
    int i = blockIdx.x * blockDim.x + threadIdx.x;
    if (i < n) p[i] = 0;
}

__global__ void k_hist(const int* __restrict__ dst, int* __restrict__ hist, int E) {
    int i = blockIdx.x * blockDim.x + threadIdx.x;
    if (i < E) atomicAdd(&hist[dst[i]], 1);
}

// dinv[i] = rsqrt(1 + in_degree)   (self-loop contributes 1)
__global__ void k_dinv(const int* __restrict__ hist, float* __restrict__ dinv, int n) {
    int i = blockIdx.x * blockDim.x + threadIdx.x;
    if (i < n) dinv[i] = rsqrtf((float)(hist[i] + 1));
}

// single-block exclusive scan of hist[0..N) -> row_off[0..N]
__global__ __launch_bounds__(1024) void k_scan(const int* __restrict__ hist,
                                               int* __restrict__ row_off, int N) {
    __shared__ int sums[1024];
    int t = threadIdx.x;
    int chunk = DIV_UP(N, 1024);
    int beg = t * chunk, end = min(beg + chunk, N);
    int s = 0;
    for (int i = beg; i < end; ++i) s += hist[i];
    sums[t] = s;
    __syncthreads();
    for (int off = 1; off < 1024; off <<= 1) {
        int v = (t >= off) ? sums[t - off] : 0;
        __syncthreads();
        sums[t] += v;
        __syncthreads();
    }
    int run = sums[t] - s;   // exclusive prefix
    for (int i = beg; i < end; ++i) { row_off[i] = run; run += hist[i]; }
    if (t == 1023) row_off[N] = sums[1023];
}

// bin edges into dst-CSR; one int atomic per edge
__global__ void k_bin(const int* __restrict__ src, const int* __restrict__ dst,
                      const int* __restrict__ row_off, int* __restrict__ cursor,
                      const float* __restrict__ dinv,
                      int* __restrict__ csr_src, float* __restrict__ csr_w, int E) {
    int i = blockIdx.x * blockDim.x + threadIdx.x;
    if (i >= E) return;
    int d = dst[i], s = src[i];
    int pos = row_off[d] + atomicAdd(&cursor[d], 1);
    csr_src[pos] = s;
    csr_w[pos] = dinv[s] * dinv[d];
}

// out[i,:] = dinv[i]^2 * H[i,:] (+bias) + sum_{j in-edges} w_j * H[src_j,:]
template <int F>
__global__ __launch_bounds__(256) void k_gather(const float* __restrict__ H,
        const int* __restrict__ row_off, const int* __restrict__ csr_src,
        const float* __restrict__ csr_w, const float* __restrict__ dinv,
        const float* __restrict__ bias, float* __restrict__ out, int N) {
    const int LPN = F / 4;            // lanes per node
    const int NPB = 256 / LPN;        // nodes per block
    int node = blockIdx.x * NPB + threadIdx.x / LPN;
    if (node >= N) return;
    int f = (threadIdx.x % LPN) << 2;
    float sc = dinv[node]; sc *= sc;
    float4 v = *(const float4*)&H[(size_t)node * F + f];
    float4 acc;
    acc.x = sc * v.x; acc.y = sc * v.y; acc.z = sc * v.z; acc.w = sc * v.w;
    if (bias) {
        acc.x += bias[f]; acc.y += bias[f + 1]; acc.z += bias[f + 2]; acc.w += bias[f + 3];
    }
    int e0 = row_off[node], e1 = row_off[node + 1];
    for (int j = e0; j < e1; ++j) {
        int s = csr_src[j];
        float w = csr_w[j];
        float4 hv = *(const float4*)&H[(size_t)s * F + f];
        acc.x = fmaf(w, hv.x, acc.x);
        acc.y = fmaf(w, hv.y, acc.y);
        acc.z = fmaf(w, hv.z, acc.z);
        acc.w = fmaf(w, hv.w, acc.w);
    }
    *(float4*)&out[(size_t)node * F + f] = acc;
}

// bounds[g] = first row with batch >= g (batch sorted); bounds[G] = N
__global__ void k_bounds(const int* __restrict__ batch, int* __restrict__ bounds,
                         int N, int G) {
    int g = blockIdx.x * blockDim.x + threadIdx.x;
    if (g > G) return;
    int lo = 0, hi = N;
    while (lo < hi) { int mid = (lo + hi) >> 1; if (batch[mid] < g) lo = mid + 1; else hi = mid; }
    bounds[g] = lo;
}

// segment_max over sorted ranges: block g, thread f
template <int F>
__global__ void k_segmax_sorted(const float* __restrict__ H, const int* __restrict__ bounds,
                                float* __restrict__ out) {
    int g = blockIdx.x;
    int f = threadIdx.x;
    int s = bounds[g], e = bounds[g + 1];
    float m = -INFINITY;
    for (int r = s; r < e; ++r) m = fmaxf(m, H[(size_t)r * F + f]);
    out[(size_t)g * F + f] = m;
}

// fp32 GEMM: C[M,NC] = act(A[M,K] @ B[K,NC] + bias). BM=BN=64, BK=16, 256 thr, 4x4 microtile.
__global__ __launch_bounds__(256) void k_gemm(const float* __restrict__ A,
                                              const float* __restrict__ B,
                                              const float* __restrict__ bias,
                                              float* __restrict__ C,
                                              int M, int K, int NC, int act) {
    __shared__ float As[16][68];
    __shared__ float Bs[16][64];
    int tid = threadIdx.x;
    int row0 = blockIdx.y * 64;
    int col0 = blockIdx.x * 64;
    int a_row = tid >> 2;
    int a_k = (tid & 3) << 2;
    int b_k = tid >> 4;
    int b_n = (tid & 15) << 2;
    int tx = tid & 15, ty = tid >> 4;
    float acc[4][4] = {{0.f}};

    for (int k0 = 0; k0 < K; k0 += 16) {
        float4 av = make_float4(0.f, 0.f, 0.f, 0.f);
        int gr = row0 + a_row;
        if (gr < M) av = *(const float4*)&A[(size_t)gr * K + k0 + a_k];
        As[a_k + 0][a_row] = av.x;
        As[a_k + 1][a_row] = av.y;
        As[a_k + 2][a_row] = av.z;
        As[a_k + 3][a_row] = av.w;
        *(float4*)&Bs[b_k][b_n] = *(const float4*)&B[(size_t)(k0 + b_k) * NC + col0 + b_n];
        __syncthreads();
#pragma unroll
        for (int kk = 0; kk < 16; ++kk) {
            float4 a = *(const float4*)&As[kk][ty << 2];
            float4 b = *(const float4*)&Bs[kk][tx << 2];
            acc[0][0] += a.x * b.x; acc[0][1] += a.x * b.y; acc[0][2] += a.x * b.z; acc[0][3] += a.x * b.w;
            acc[1][0] += a.y * b.x; acc[1][1] += a.y * b.y; acc[1][2] += a.y * b.z; acc[1][3] += a.y * b.w;
            acc[2][0] += a.z * b.x; acc[2][1] += a.z * b.y; acc[2][2] += a.z * b.z; acc[2][3] += a.z * b.w;
            acc[3][0] += a.w * b.x; acc[3][1] += a.w * b.y; acc[3][2] += a.w * b.z; acc[3][3] += a.w * b.w;
        }
        __syncthreads();
    }

#pragma unroll
    for (int i = 0; i < 4; ++i) {
        int r = row0 + (ty << 2) + i;
        if (r >= M) continue;
        int c0 = col0 + (tx << 2);
        float4 o;
        float* pa = acc[i];
        o.x = pa[0]; o.y = pa[1]; o.z = pa[2]; o.w = pa[3];
        if (bias) { o.x += bias[c0]; o.y += bias[c0 + 1]; o.z += bias[c0 + 2]; o.w += bias[c0 + 3]; }
        if (act) {
            o.x = (o.x >= 0.f) ? o.x : 0.01f * o.x;
            o.y = (o.y >= 0.f) ? o.y : 0.01f * o.y;
            o.z = (o.z >= 0.f) ? o.z : 0.01f * o.z;
            o.w = (o.w >= 0.f) ? o.w : 0.01f * o.w;
        }
        *(float4*)&C[(size_t)r * NC + c0] = o;
    }
}

// narrow GEMM NC=32: W staged in LDS
__global__ __launch_bounds__(256) void k_gemm_n32(const float* __restrict__ A,
                                                  const float* __restrict__ W,
                                                  const float* __restrict__ bias,
                                                  float* __restrict__ C, int M, int K) {
    __shared__ float Ws[128 * 32];
    int tid = threadIdx.x;
    for (int i = tid; i < K * 32; i += 256) Ws[i] = W[i];
    __syncthreads();
    int row = blockIdx.x * 8 + (tid >> 5);
    int col = tid & 31;
    if (row >= M) return;
    float acc = bias[col];
    const float* a = &A[(size_t)row * K];
    for (int k = 0; k < K; ++k) acc = fmaf(a[k], Ws[k * 32 + col], acc);
    C[(size_t)row * 32 + col] = acc;
}

// per-graph: z = Z4[r,:32] @ W5 + b5, reduce max over rows of the graph. No atomics.
__global__ __launch_bounds__(320) void k_z5_segmax(const float* __restrict__ Z,
        const float* __restrict__ W, const float* __restrict__ bias,
        const int* __restrict__ bounds, float* __restrict__ out) {
    __shared__ float Ws[320];
    __shared__ float red[320];
    int t = threadIdx.x;
    Ws[t] = W[t];
    __syncthreads();
    int g = blockIdx.x;
    int col = t % 10, rs = t / 10;
    float bcol = bias[col];
    int s = bounds[g], e = bounds[g + 1];
    float m = -INFINITY;
    for (int r = s + rs; r < e; r += 32) {
        float acc = bcol;
        const float* a = &Z[(size_t)r * 32];
#pragma unroll
        for (int k = 0; k < 32; ++k) acc = fmaf(a[k], Ws[k * 10 + col], acc);
        m = fmaxf(m, acc);
    }
    red[t] = m;
    __syncthreads();
    for (int step = 16; step >= 1; step >>= 1) {
        if (rs < step && t < 320) {
            red[rs * 10 + col] = fmaxf(red[rs * 10 + col], red[(rs + step) * 10 + col]);
        }
        __syncthreads();
    }
    if (rs == 0) out[(size_t)g * 10 + col] = red[col];
}

extern "C" void kernel_launch(void* const* d_in, const int* in_sizes, int n_in,
                              void* d_out, int out_size, void* d_ws, size_t ws_size,
                              hipStream_t stream) {
    const float* x  = (const float*)d_in[0];
    const int* ei   = (const int*)d_in[1];
    const int* batch= (const int*)d_in[2];
    const float* W1 = (const float*)d_in[3];
    const float* b1 = (const float*)d_in[4];
    const float* W2 = (const float*)d_in[5];
    const float* b2 = (const float*)d_in[6];
    const float* W3 = (const float*)d_in[7];
    const float* b3 = (const float*)d_in[8];
    const float* W4 = (const float*)d_in[9];
    const float* b4 = (const float*)d_in[10];
    const float* W5 = (const float*)d_in[11];
    const float* b5 = (const float*)d_in[12];

    const int N  = in_sizes[2];           // 50000
    const int F  = in_sizes[0] / N;       // 128
    const int E  = in_sizes[1] / 2;       // 400000
    const int C1 = in_sizes[4];           // 512
    const int C2 = in_sizes[6];           // 256
    const int C3 = in_sizes[8];           // 128
    const int C5 = in_sizes[12];          // 10
    const int G  = out_size / (C2 + C5);  // 512

    const int* srcp = ei;
    const int* dstp = ei + E;

    // ---- workspace layout ----
    char* w = (char*)d_ws;
    int* hist    = (int*)w;              w += sizeof(int) * N;
    int* row_off = (int*)w;              w += sizeof(int) * (N + 1);
    int* cursor  = (int*)w;              w += sizeof(int) * N;
    int* bounds  = (int*)w;              w += sizeof(int) * (G + 1);
    int* csr_src = (int*)w;              w += sizeof(int) * E;
    float* csr_w = (float*)w;            w += sizeof(float) * E;
    float* dinv  = (float*)w;            w += sizeof(float) * N;
    float* aggx  = (float*)w;            w += sizeof(float) * (size_t)N * F;   // reused as z3
    float* h1    = (float*)w;            w += sizeof(float) * (size_t)N * C1;  // reused: h2, z4
    float* t2    = (float*)w;            w += sizeof(float) * (size_t)N * C2;
    float* h2 = h1;
    float* z3 = aggx;
    float* z4 = h1 + (size_t)N * C2;

    float* out     = (float*)d_out;
    float* out_emb = out + (size_t)G * C5;

    // ---- CSR build (int atomics only) + dinv + graph bounds ----
    k_zero_i<<<DIV_UP(2 * N, 256), 256, 0, stream>>>(hist, 2 * N);  // hist + cursor adjacency? no:
    // (hist and cursor are not adjacent; zero separately)
    k_zero_i<<<DIV_UP(N, 256), 256, 0, stream>>>(cursor, N);
    k_hist<<<DIV_UP(E, 256), 256, 0, stream>>>(dstp, hist, E);
    k_scan<<<1, 1024, 0, stream>>>(hist, row_off, N);
    k_dinv<<<DIV_UP(N, 256), 256, 0, stream>>>(hist, dinv, N);
    k_bin<<<DIV_UP(E, 256), 256, 0, stream>>>(srcp, dstp, row_off, cursor, dinv,
                                              csr_src, csr_w, E);
    k_bounds<<<DIV_UP(G + 1, 256), 256, 0, stream>>>(batch, bounds, N, G);

    // ---- layer 1: aggregate x (128-dim) via gather, then GEMM+bias+leakyrelu ----
    k_gather<128><<<DIV_UP(N, 8), 256, 0, stream>>>(x, row_off, csr_src, csr_w, dinv,
                                                    nullptr, aggx, N);
    dim3 g1(C1 / 64, DIV_UP(N, 64));
    k_gemm<<<g1, 256, 0, stream>>>(aggx, W1, b1, h1, N, F, C1, 1);

    // ---- layer 2: GEMM first (256-dim), then gather-aggregate (+b2, self-loop fused) ----
    dim3 g2(C2 / 64, DIV_UP(N, 64));
    k_gemm<<<g2, 256, 0, stream>>>(h1, W2, nullptr, t2, N, C1, C2, 0);
    k_gather<256><<<DIV_UP(N, 4), 256, 0, stream>>>(t2, row_off, csr_src, csr_w, dinv,
                                                    b2, h2, N);

    // ---- embs = segment_max(h2) over sorted batch ranges ----
    k_segmax_sorted<256><<<G, 256, 0, stream>>>(h2, bounds, out_emb);

    // ---- MLP head + fused segment_max ----
    dim3 g3(C3 / 64, DIV_UP(N, 64));
    k_gemm<<<g3, 256, 0, stream>>>(h2, W3, b3, z3, N, C2, C3, 0);
    k_gemm_n32<<<DIV_UP(N, 8), 256, 0, stream>>>(z3, W4, b4, z4, N, C3);
    k_z5_segmax<<<G, 320, 0, stream>>>(z4, W5, b5, bounds, out);
}

// Round 3
// 469.191 us; speedup vs baseline: 5.6022x; 1.7246x over previous
//
#include <hip/hip_runtime.h>
#include <math.h>

#define DIV_UP(a,b) (((a)+(b)-1)/(b))

typedef __attribute__((ext_vector_type(8))) short bf16x8;
typedef __attribute__((ext_vector_type(4))) float f32x4;

// fp32 -> bf16 round-to-nearest-even
__device__ inline unsigned short f2b(float x) {
    unsigned int u = __float_as_uint(x);
    u += 0x7fffu + ((u >> 16) & 1u);
    return (unsigned short)(u >> 16);
}

// 8 packed bf16 (uint4) -> 8 floats
__device__ inline void cvt8(uint4 v, float* a) {
    a[0] = __uint_as_float(v.x << 16); a[1] = __uint_as_float(v.x & 0xffff0000u);
    a[2] = __uint_as_float(v.y << 16); a[3] = __uint_as_float(v.y & 0xffff0000u);
    a[4] = __uint_as_float(v.z << 16); a[5] = __uint_as_float(v.z & 0xffff0000u);
    a[6] = __uint_as_float(v.w << 16); a[7] = __uint_as_float(v.w & 0xffff0000u);
}

__global__ void k_zero_i(int* p, int n) {
    int i = blockIdx.x * blockDim.x + threadIdx.x;
    if (i < n) p[i] = 0;
}

__global__ void k_hist(const int* __restrict__ dst, int* __restrict__ hist, int E) {
    int i = blockIdx.x * blockDim.x + threadIdx.x;
    if (i < E) atomicAdd(&hist[dst[i]], 1);
}

__global__ void k_dinv(const int* __restrict__ hist, float* __restrict__ dinv, int n) {
    int i = blockIdx.x * blockDim.x + threadIdx.x;
    if (i < n) dinv[i] = rsqrtf((float)(hist[i] + 1));
}

// single-block exclusive scan of hist[0..N) -> row_off[0..N]
__global__ __launch_bounds__(1024) void k_scan(const int* __restrict__ hist,
                                               int* __restrict__ row_off, int N) {
    __shared__ int sums[1024];
    int t = threadIdx.x;
    int chunk = DIV_UP(N, 1024);
    int beg = t * chunk, end = min(beg + chunk, N);
    int s = 0;
    for (int i = beg; i < end; ++i) s += hist[i];
    sums[t] = s;
    __syncthreads();
    for (int off = 1; off < 1024; off <<= 1) {
        int v = (t >= off) ? sums[t - off] : 0;
        __syncthreads();
        sums[t] += v;
        __syncthreads();
    }
    int run = sums[t] - s;
    for (int i = beg; i < end; ++i) { row_off[i] = run; run += hist[i]; }
    if (t == 1023) row_off[N] = sums[1023];
}

__global__ void k_bin(const int* __restrict__ src, const int* __restrict__ dst,
                      const int* __restrict__ row_off, int* __restrict__ cursor,
                      const float* __restrict__ dinv,
                      int* __restrict__ csr_src, float* __restrict__ csr_w, int E) {
    int i = blockIdx.x * blockDim.x + threadIdx.x;
    if (i >= E) return;
    int d = dst[i], s = src[i];
    int pos = row_off[d] + atomicAdd(&cursor[d], 1);
    csr_src[pos] = s;
    csr_w[pos] = dinv[s] * dinv[d];
}

__global__ void k_bounds(const int* __restrict__ batch, int* __restrict__ bounds,
                         int N, int G) {
    int g = blockIdx.x * blockDim.x + threadIdx.x;
    if (g > G) return;
    int lo = 0, hi = N;
    while (lo < hi) { int mid = (lo + hi) >> 1; if (batch[mid] < g) lo = mid + 1; else hi = mid; }
    bounds[g] = lo;
}

// fp32[4] -> bf16[4] elementwise convert
__global__ void k_f2b4(const float* __restrict__ in, unsigned short* __restrict__ out, int n4) {
    int i = blockIdx.x * blockDim.x + threadIdx.x;
    if (i >= n4) return;
    float4 v = ((const float4*)in)[i];
    ushort4 o;
    o.x = f2b(v.x); o.y = f2b(v.y); o.z = f2b(v.z); o.w = f2b(v.w);
    ((ushort4*)out)[i] = o;
}

// weight transpose+convert: out_bf16[n*K + k] = in[k*NC + n]
__global__ void k_wt(const float* __restrict__ in, unsigned short* __restrict__ out,
                     int K, int NC) {
    int i = blockIdx.x * blockDim.x + threadIdx.x;
    if (i >= K * NC) return;
    int k = i / NC, n = i % NC;
    out[(size_t)n * K + k] = f2b(in[i]);
}

// gather-aggregate over dst-CSR, bf16 in, optional fp32 and/or bf16 out.
// out[i,:] = dinv[i]^2*H[i,:] (+bias) + sum_j w_j*H[src_j,:]
template <int F, int WF32, int WB16>
__global__ __launch_bounds__(256) void k_gather_b(const unsigned short* __restrict__ H,
        const int* __restrict__ row_off, const int* __restrict__ csr_src,
        const float* __restrict__ csr_w, const float* __restrict__ dinv,
        const float* __restrict__ bias, float* __restrict__ outf,
        unsigned short* __restrict__ outb, int N) {
    const int LPN = F / 8;
    const int NPB = 256 / LPN;
    int node = blockIdx.x * NPB + threadIdx.x / LPN;
    if (node >= N) return;
    int f = (threadIdx.x % LPN) * 8;
    float sc = dinv[node]; sc *= sc;
    float a[8];
    cvt8(*(const uint4*)&H[(size_t)node * F + f], a);
#pragma unroll
    for (int j = 0; j < 8; ++j) a[j] *= sc;
    if (bias) {
#pragma unroll
        for (int j = 0; j < 8; ++j) a[j] += bias[f + j];
    }
    int e0 = row_off[node], e1 = row_off[node + 1];
    for (int e = e0; e < e1; ++e) {
        int s = csr_src[e];
        float w = csr_w[e];
        float b[8];
        cvt8(*(const uint4*)&H[(size_t)s * F + f], b);
#pragma unroll
        for (int j = 0; j < 8; ++j) a[j] = fmaf(w, b[j], a[j]);
    }
    if (WF32) {
        float4 o0 = make_float4(a[0], a[1], a[2], a[3]);
        float4 o1 = make_float4(a[4], a[5], a[6], a[7]);
        *(float4*)&outf[(size_t)node * F + f] = o0;
        *(float4*)&outf[(size_t)node * F + f + 4] = o1;
    }
    if (WB16) {
        uint4 o;
        o.x = (unsigned)f2b(a[0]) | ((unsigned)f2b(a[1]) << 16);
        o.y = (unsigned)f2b(a[2]) | ((unsigned)f2b(a[3]) << 16);
        o.z = (unsigned)f2b(a[4]) | ((unsigned)f2b(a[5]) << 16);
        o.w = (unsigned)f2b(a[6]) | ((unsigned)f2b(a[7]) << 16);
        *(uint4*)&outb[(size_t)node * F + f] = o;
    }
}

// bf16 MFMA GEMM: C[M,NC] = act(A[M,K] @ B[K,NC] + bias)
// A bf16 row-major [M,K]; Bt bf16 TRANSPOSED [NC,K]. 128x128 tile, BK=32,
// 4 waves (2x2), each wave 64x64 via 4x4 grid of 16x16x32 MFMAs.
template <int OUT_BF16, int ACT>
__global__ __launch_bounds__(256) void k_gemm_mfma(const unsigned short* __restrict__ A,
        const unsigned short* __restrict__ Bt, const float* __restrict__ bias,
        void* __restrict__ Cout, int M, int K, int NC) {
    __shared__ __align__(16) unsigned short As[128][40];  // k padded 32->40 (stride 80B, 16B-mult)
    __shared__ __align__(16) unsigned short Bs[128][40];  // n-major
    int tid = threadIdx.x;
    int wave = tid >> 6, lane = tid & 63;
    int row0 = blockIdx.y * 128, col0 = blockIdx.x * 128;
    int wr = (wave >> 1) * 64, wc = (wave & 1) * 64;
    f32x4 acc[4][4] = {};
    int sr = tid >> 2;            // 0..63
    int sk = (tid & 3) * 8;       // 0,8,16,24
    int lr = lane & 15;
    int lq = (lane >> 4) * 8;

    for (int k0 = 0; k0 < K; k0 += 32) {
#pragma unroll
        for (int i = 0; i < 2; ++i) {
            int r = sr + i * 64;
            int gr = min(row0 + r, M - 1);          // clamp: OOB rows never stored
            *(uint4*)&As[r][sk] = *(const uint4*)&A[(size_t)gr * K + k0 + sk];
            *(uint4*)&Bs[r][sk] = *(const uint4*)&Bt[(size_t)(col0 + r) * K + k0 + sk];
        }
        __syncthreads();
        bf16x8 af[4], bfv[4];
#pragma unroll
        for (int i = 0; i < 4; ++i) af[i] = *(const bf16x8*)&As[wr + i * 16 + lr][lq];
#pragma unroll
        for (int j = 0; j < 4; ++j) bfv[j] = *(const bf16x8*)&Bs[wc + j * 16 + lr][lq];
#pragma unroll
        for (int i = 0; i < 4; ++i)
#pragma unroll
            for (int j = 0; j < 4; ++j)
                acc[i][j] = __builtin_amdgcn_mfma_f32_16x16x32_bf16(af[i], bfv[j], acc[i][j], 0, 0, 0);
        __syncthreads();
    }

    int lq4 = (lane >> 4) * 4;
#pragma unroll
    for (int i = 0; i < 4; ++i) {
#pragma unroll
        for (int r = 0; r < 4; ++r) {
            int row = row0 + wr + i * 16 + lq4 + r;
            if (row >= M) continue;
#pragma unroll
            for (int j = 0; j < 4; ++j) {
                int col = col0 + wc + j * 16 + lr;
                float v = acc[i][j][r];
                if (bias) v += bias[col];
                if (ACT) v = (v >= 0.f) ? v : 0.01f * v;
                if (OUT_BF16)
                    ((unsigned short*)Cout)[(size_t)row * NC + col] = f2b(v);
                else
                    ((float*)Cout)[(size_t)row * NC + col] = v;
            }
        }
    }
}

// segment_max over sorted ranges: block g, thread f
template <int F>
__global__ void k_segmax_sorted(const float* __restrict__ H, const int* __restrict__ bounds,
                                float* __restrict__ out) {
    int g = blockIdx.x;
    int f = threadIdx.x;
    int s = bounds[g], e = bounds[g + 1];
    float m = -INFINITY;
    for (int r = s; r < e; ++r) m = fmaxf(m, H[(size_t)r * F + f]);
    out[(size_t)g * F + f] = m;
}

// narrow fp32 GEMM NC=32, W staged in LDS
__global__ __launch_bounds__(256) void k_gemm_n32(const float* __restrict__ A,
                                                  const float* __restrict__ W,
                                                  const float* __restrict__ bias,
                                                  float* __restrict__ C, int M, int K) {
    __shared__ float Ws[128 * 32];
    int tid = threadIdx.x;
    for (int i = tid; i < K * 32; i += 256) Ws[i] = W[i];
    __syncthreads();
    int row = blockIdx.x * 8 + (tid >> 5);
    int col = tid & 31;
    if (row >= M) return;
    float acc = bias[col];
    const float* a = &A[(size_t)row * K];
    for (int k = 0; k < K; ++k) acc = fmaf(a[k], Ws[k * 32 + col], acc);
    C[(size_t)row * 32 + col] = acc;
}

// per-graph: z = Z[r,:32] @ W5 + b5, max over graph rows
__global__ __launch_bounds__(320) void k_z5_segmax(const float* __restrict__ Z,
        const float* __restrict__ W, const float* __restrict__ bias,
        const int* __restrict__ bounds, float* __restrict__ out) {
    __shared__ float Ws[320];
    __shared__ float red[320];
    int t = threadIdx.x;
    Ws[t] = W[t];
    __syncthreads();
    int g = blockIdx.x;
    int col = t % 10, rs = t / 10;
    float bcol = bias[col];
    int s = bounds[g], e = bounds[g + 1];
    float m = -INFINITY;
    for (int r = s + rs; r < e; r += 32) {
        float acc = bcol;
        const float* a = &Z[(size_t)r * 32];
#pragma unroll
        for (int k = 0; k < 32; ++k) acc = fmaf(a[k], Ws[k * 10 + col], acc);
        m = fmaxf(m, acc);
    }
    red[t] = m;
    __syncthreads();
    for (int step = 16; step >= 1; step >>= 1) {
        if (rs < step) red[rs * 10 + col] = fmaxf(red[rs * 10 + col], red[(rs + step) * 10 + col]);
        __syncthreads();
    }
    if (rs == 0) out[(size_t)g * 10 + col] = red[col];
}

extern "C" void kernel_launch(void* const* d_in, const int* in_sizes, int n_in,
                              void* d_out, int out_size, void* d_ws, size_t ws_size,
                              hipStream_t stream) {
    const float* x  = (const float*)d_in[0];
    const int* ei   = (const int*)d_in[1];
    const int* batch= (const int*)d_in[2];
    const float* W1 = (const float*)d_in[3];
    const float* b1 = (const float*)d_in[4];
    const float* W2 = (const float*)d_in[5];
    const float* b2 = (const float*)d_in[6];
    const float* W3 = (const float*)d_in[7];
    const float* b3 = (const float*)d_in[8];
    const float* W4 = (const float*)d_in[9];
    const float* b4 = (const float*)d_in[10];
    const float* W5 = (const float*)d_in[11];
    const float* b5 = (const float*)d_in[12];

    const int N  = in_sizes[2];           // 50000
    const int F  = in_sizes[0] / N;       // 128
    const int E  = in_sizes[1] / 2;       // 400000
    const int C1 = in_sizes[4];           // 512
    const int C2 = in_sizes[6];           // 256
    const int C3 = in_sizes[8];           // 128
    const int C5 = in_sizes[12];          // 10
    const int G  = out_size / (C2 + C5);  // 512

    const int* srcp = ei;
    const int* dstp = ei + E;

    // ---- workspace layout (256B-aligned carve-outs) ----
    uintptr_t p = (uintptr_t)d_ws;
    auto carve = [&](size_t bytes) {
        uintptr_t r = p;
        p += (bytes + 255) & ~(size_t)255;
        return (void*)r;
    };
    int* hist    = (int*)carve(sizeof(int) * N);
    int* row_off = (int*)carve(sizeof(int) * (N + 1));
    int* cursor  = (int*)carve(sizeof(int) * N);
    int* bounds  = (int*)carve(sizeof(int) * (G + 1));
    int* csr_src = (int*)carve(sizeof(int) * E);
    float* csr_w = (float*)carve(sizeof(float) * E);
    float* dinv  = (float*)carve(sizeof(float) * N);
    unsigned short* w1t = (unsigned short*)carve(sizeof(short) * F * C1);
    unsigned short* w2t = (unsigned short*)carve(sizeof(short) * C1 * C2);
    unsigned short* w3t = (unsigned short*)carve(sizeof(short) * C2 * C3);
    unsigned short* xb    = (unsigned short*)carve(sizeof(short) * (size_t)N * F);
    unsigned short* aggxb = (unsigned short*)carve(sizeof(short) * (size_t)N * F);
    unsigned short* h1b   = (unsigned short*)carve(sizeof(float) * (size_t)N * C2); // N*512 bf16 == N*256 f32; reused as h2f
    unsigned short* t2b   = (unsigned short*)carve(sizeof(short) * (size_t)N * C2); // reused as z4 (N*32 f32 fits)
    unsigned short* h2b   = (unsigned short*)carve(sizeof(short) * (size_t)N * C2);
    float* z3 = (float*)carve(sizeof(float) * (size_t)N * C3);
    float* h2f = (float*)h1b;
    float* z4  = (float*)t2b;

    float* out     = (float*)d_out;
    float* out_emb = out + (size_t)G * C5;

    // ---- CSR build + dinv + graph bounds ----
    k_zero_i<<<DIV_UP(N, 256), 256, 0, stream>>>(hist, N);
    k_zero_i<<<DIV_UP(N, 256), 256, 0, stream>>>(cursor, N);
    k_hist<<<DIV_UP(E, 256), 256, 0, stream>>>(dstp, hist, E);
    k_scan<<<1, 1024, 0, stream>>>(hist, row_off, N);
    k_dinv<<<DIV_UP(N, 256), 256, 0, stream>>>(hist, dinv, N);
    k_bin<<<DIV_UP(E, 256), 256, 0, stream>>>(srcp, dstp, row_off, cursor, dinv,
                                              csr_src, csr_w, E);
    k_bounds<<<DIV_UP(G + 1, 256), 256, 0, stream>>>(batch, bounds, N, G);

    // ---- bf16 conversions ----
    k_f2b4<<<DIV_UP(N * F / 4, 256), 256, 0, stream>>>(x, xb, N * F / 4);
    k_wt<<<DIV_UP(F * C1, 256), 256, 0, stream>>>(W1, w1t, F, C1);
    k_wt<<<DIV_UP(C1 * C2, 256), 256, 0, stream>>>(W2, w2t, C1, C2);
    k_wt<<<DIV_UP(C2 * C3, 256), 256, 0, stream>>>(W3, w3t, C2, C3);

    // ---- layer 1: gather (bf16) -> MFMA GEMM + bias + leakyrelu -> h1 bf16 ----
    k_gather_b<128, 0, 1><<<DIV_UP(N, 16), 256, 0, stream>>>(
        xb, row_off, csr_src, csr_w, dinv, nullptr, nullptr, aggxb, N);
    dim3 g1(C1 / 128, DIV_UP(N, 128));
    k_gemm_mfma<1, 1><<<g1, 256, 0, stream>>>(aggxb, w1t, b1, h1b, N, F, C1);

    // ---- layer 2: MFMA GEMM -> t2 bf16 -> gather (+b2) -> h2 fp32 + bf16 ----
    dim3 g2(C2 / 128, DIV_UP(N, 128));
    k_gemm_mfma<1, 0><<<g2, 256, 0, stream>>>(h1b, w2t, nullptr, t2b, N, C1, C2);
    k_gather_b<256, 1, 1><<<DIV_UP(N, 8), 256, 0, stream>>>(
        t2b, row_off, csr_src, csr_w, dinv, b2, h2f, h2b, N);

    // ---- embs = segment_max(h2) ----
    k_segmax_sorted<256><<<G, 256, 0, stream>>>(h2f, bounds, out_emb);

    // ---- MLP head: MFMA L3 (fp32 out) -> fp32 n32 -> fused z5+segmax ----
    dim3 g3(C3 / 128, DIV_UP(N, 128));
    k_gemm_mfma<0, 0><<<g3, 256, 0, stream>>>(h2b, w3t, b3, z3, N, C2, C3);
    k_gemm_n32<<<DIV_UP(N, 8), 256, 0, stream>>>(z3, W4, b4, z4, N, C3);
    k_z5_segmax<<<G, 320, 0, stream>>>(z4, W5, b5, bounds, out);
}

// Round 4
// 395.085 us; speedup vs baseline: 6.6530x; 1.1876x over previous
//
#include <hip/hip_runtime.h>
#include <math.h>

#define DIV_UP(a,b) (((a)+(b)-1)/(b))

typedef __attribute__((ext_vector_type(8))) short bf16x8;
typedef __attribute__((ext_vector_type(4))) float f32x4;

// fp32 -> bf16 round-to-nearest-even
__device__ inline unsigned short f2b(float x) {
    unsigned int u = __float_as_uint(x);
    u += 0x7fffu + ((u >> 16) & 1u);
    return (unsigned short)(u >> 16);
}

// 8 packed bf16 (uint4) -> 8 floats
__device__ inline void cvt8(uint4 v, float* a) {
    a[0] = __uint_as_float(v.x << 16); a[1] = __uint_as_float(v.x & 0xffff0000u);
    a[2] = __uint_as_float(v.y << 16); a[3] = __uint_as_float(v.y & 0xffff0000u);
    a[4] = __uint_as_float(v.z << 16); a[5] = __uint_as_float(v.z & 0xffff0000u);
    a[6] = __uint_as_float(v.w << 16); a[7] = __uint_as_float(v.w & 0xffff0000u);
}

__global__ void k_zero_i(int* p, int n) {
    int i = blockIdx.x * blockDim.x + threadIdx.x;
    if (i < n) p[i] = 0;
}

__global__ void k_hist(const int* __restrict__ dst, int* __restrict__ hist, int E) {
    int i = blockIdx.x * blockDim.x + threadIdx.x;
    if (i < E) atomicAdd(&hist[dst[i]], 1);
}

__global__ void k_dinv(const int* __restrict__ hist, float* __restrict__ dinv, int n) {
    int i = blockIdx.x * blockDim.x + threadIdx.x;
    if (i < n) dinv[i] = rsqrtf((float)(hist[i] + 1));
}

// ---- hierarchical scan: 1024 elements per block ----
__global__ __launch_bounds__(256) void k_scan_bsum(const int* __restrict__ hist,
                                                   int* __restrict__ bsum, int N) {
    __shared__ int red[256];
    int t = threadIdx.x;
    int base = blockIdx.x * 1024 + t * 4;
    int s = 0;
    if (base + 3 < N) {
        int4 v = *(const int4*)&hist[base];
        s = v.x + v.y + v.z + v.w;
    } else {
        for (int j = 0; j < 4; ++j) if (base + j < N) s += hist[base + j];
    }
    red[t] = s;
    __syncthreads();
    for (int off = 128; off >= 1; off >>= 1) {
        if (t < off) red[t] += red[t + off];
        __syncthreads();
    }
    if (t == 0) bsum[blockIdx.x] = red[0];
}

// single block scans NB (<=1024) block sums -> exclusive boff; writes row_off[N]=total
__global__ __launch_bounds__(1024) void k_scan_boff(const int* __restrict__ bsum,
        int* __restrict__ boff, int* __restrict__ row_off, int NB, int N) {
    __shared__ int s[1024];
    int t = threadIdx.x;
    int v = (t < NB) ? bsum[t] : 0;
    s[t] = v;
    __syncthreads();
    for (int off = 1; off < 1024; off <<= 1) {
        int u = (t >= off) ? s[t - off] : 0;
        __syncthreads();
        s[t] += u;
        __syncthreads();
    }
    if (t < NB) boff[t] = s[t] - v;
    if (t == NB - 1) row_off[N] = s[t];
}

__global__ __launch_bounds__(256) void k_scan_apply(const int* __restrict__ hist,
        const int* __restrict__ boff, int* __restrict__ row_off, int N) {
    __shared__ int s[256];
    int t = threadIdx.x;
    int base = blockIdx.x * 1024 + t * 4;
    int v[4];
    int loc = 0;
#pragma unroll
    for (int j = 0; j < 4; ++j) { v[j] = (base + j < N) ? hist[base + j] : 0; loc += v[j]; }
    s[t] = loc;
    __syncthreads();
    for (int off = 1; off < 256; off <<= 1) {
        int u = (t >= off) ? s[t - off] : 0;
        __syncthreads();
        s[t] += u;
        __syncthreads();
    }
    int run = boff[blockIdx.x] + s[t] - loc;   // exclusive prefix for this thread
#pragma unroll
    for (int j = 0; j < 4; ++j) {
        if (base + j < N) row_off[base + j] = run;
        run += v[j];
    }
}

__global__ void k_bin(const int* __restrict__ src, const int* __restrict__ dst,
                      const int* __restrict__ row_off, int* __restrict__ cursor,
                      const float* __restrict__ dinv,
                      int* __restrict__ csr_src, float* __restrict__ csr_w, int E) {
    int i = blockIdx.x * blockDim.x + threadIdx.x;
    if (i >= E) return;
    int d = dst[i], s = src[i];
    int pos = row_off[d] + atomicAdd(&cursor[d], 1);
    csr_src[pos] = s;
    csr_w[pos] = dinv[s] * dinv[d];
}

__global__ void k_bounds(const int* __restrict__ batch, int* __restrict__ bounds,
                         int N, int G) {
    int g = blockIdx.x * blockDim.x + threadIdx.x;
    if (g > G) return;
    int lo = 0, hi = N;
    while (lo < hi) { int mid = (lo + hi) >> 1; if (batch[mid] < g) lo = mid + 1; else hi = mid; }
    bounds[g] = lo;
}

// fp32[4] -> bf16[4] elementwise convert
__global__ void k_f2b4(const float* __restrict__ in, unsigned short* __restrict__ out, int n4) {
    int i = blockIdx.x * blockDim.x + threadIdx.x;
    if (i >= n4) return;
    float4 v = ((const float4*)in)[i];
    ushort4 o;
    o.x = f2b(v.x); o.y = f2b(v.y); o.z = f2b(v.z); o.w = f2b(v.w);
    ((ushort4*)out)[i] = o;
}

// weight transpose+convert: out_bf16[n*K + k] = in[k*NC + n]
__global__ void k_wt(const float* __restrict__ in, unsigned short* __restrict__ out,
                     int K, int NC) {
    int i = blockIdx.x * blockDim.x + threadIdx.x;
    if (i >= K * NC) return;
    int k = i / NC, n = i % NC;
    out[(size_t)n * K + k] = f2b(in[i]);
}

// gather-aggregate over dst-CSR, bf16 in, optional fp32 and/or bf16 out.
template <int F, int WF32, int WB16>
__global__ __launch_bounds__(256) void k_gather_b(const unsigned short* __restrict__ H,
        const int* __restrict__ row_off, const int* __restrict__ csr_src,
        const float* __restrict__ csr_w, const float* __restrict__ dinv,
        const float* __restrict__ bias, float* __restrict__ outf,
        unsigned short* __restrict__ outb, int N) {
    const int LPN = F / 8;
    const int NPB = 256 / LPN;
    int node = blockIdx.x * NPB + threadIdx.x / LPN;
    if (node >= N) return;
    int f = (threadIdx.x % LPN) * 8;
    float sc = dinv[node]; sc *= sc;
    float a[8];
    cvt8(*(const uint4*)&H[(size_t)node * F + f], a);
#pragma unroll
    for (int j = 0; j < 8; ++j) a[j] *= sc;
    if (bias) {
#pragma unroll
        for (int j = 0; j < 8; ++j) a[j] += bias[f + j];
    }
    int e0 = row_off[node], e1 = row_off[node + 1];
    for (int e = e0; e < e1; ++e) {
        int s = csr_src[e];
        float w = csr_w[e];
        float b[8];
        cvt8(*(const uint4*)&H[(size_t)s * F + f], b);
#pragma unroll
        for (int j = 0; j < 8; ++j) a[j] = fmaf(w, b[j], a[j]);
    }
    if (WF32) {
        *(float4*)&outf[(size_t)node * F + f] = make_float4(a[0], a[1], a[2], a[3]);
        *(float4*)&outf[(size_t)node * F + f + 4] = make_float4(a[4], a[5], a[6], a[7]);
    }
    if (WB16) {
        uint4 o;
        o.x = (unsigned)f2b(a[0]) | ((unsigned)f2b(a[1]) << 16);
        o.y = (unsigned)f2b(a[2]) | ((unsigned)f2b(a[3]) << 16);
        o.z = (unsigned)f2b(a[4]) | ((unsigned)f2b(a[5]) << 16);
        o.w = (unsigned)f2b(a[6]) | ((unsigned)f2b(a[7]) << 16);
        *(uint4*)&outb[(size_t)node * F + f] = o;
    }
}

// bf16 MFMA GEMM: C[M,NC] = act(A[M,K] @ B[K,NC] + bias)
// A bf16 row-major [M,K]; Bt bf16 TRANSPOSED [NC,K]. 128x128 tile, BK=32,
// 4 waves (2x2), each wave 64x64 via 4x4 grid of 16x16x32 MFMAs.
template <int OUT_BF16, int ACT>
__global__ __launch_bounds__(256) void k_gemm_mfma(const unsigned short* __restrict__ A,
        const unsigned short* __restrict__ Bt, const float* __restrict__ bias,
        void* __restrict__ Cout, int M, int K, int NC) {
    __shared__ __align__(16) unsigned short As[128][40];
    __shared__ __align__(16) unsigned short Bs[128][40];
    int tid = threadIdx.x;
    int wave = tid >> 6, lane = tid & 63;
    int row0 = blockIdx.y * 128, col0 = blockIdx.x * 128;
    int wr = (wave >> 1) * 64, wc = (wave & 1) * 64;
    f32x4 acc[4][4] = {};
    int sr = tid >> 2;
    int sk = (tid & 3) * 8;
    int lr = lane & 15;
    int lq = (lane >> 4) * 8;

    for (int k0 = 0; k0 < K; k0 += 32) {
#pragma unroll
        for (int i = 0; i < 2; ++i) {
            int r = sr + i * 64;
            int gr = min(row0 + r, M - 1);
            *(uint4*)&As[r][sk] = *(const uint4*)&A[(size_t)gr * K + k0 + sk];
            *(uint4*)&Bs[r][sk] = *(const uint4*)&Bt[(size_t)(col0 + r) * K + k0 + sk];
        }
        __syncthreads();
        bf16x8 af[4], bfv[4];
#pragma unroll
        for (int i = 0; i < 4; ++i) af[i] = *(const bf16x8*)&As[wr + i * 16 + lr][lq];
#pragma unroll
        for (int j = 0; j < 4; ++j) bfv[j] = *(const bf16x8*)&Bs[wc + j * 16 + lr][lq];
#pragma unroll
        for (int i = 0; i < 4; ++i)
#pragma unroll
            for (int j = 0; j < 4; ++j)
                acc[i][j] = __builtin_amdgcn_mfma_f32_16x16x32_bf16(af[i], bfv[j], acc[i][j], 0, 0, 0);
        __syncthreads();
    }

    int lq4 = (lane >> 4) * 4;
#pragma unroll
    for (int i = 0; i < 4; ++i) {
#pragma unroll
        for (int r = 0; r < 4; ++r) {
            int row = row0 + wr + i * 16 + lq4 + r;
            if (row >= M) continue;
#pragma unroll
            for (int j = 0; j < 4; ++j) {
                int col = col0 + wc + j * 16 + lr;
                float v = acc[i][j][r];
                if (bias) v += bias[col];
                if (ACT) v = (v >= 0.f) ? v : 0.01f * v;
                if (OUT_BF16)
                    ((unsigned short*)Cout)[(size_t)row * NC + col] = f2b(v);
                else
                    ((float*)Cout)[(size_t)row * NC + col] = v;
            }
        }
    }
}

// segment_max over sorted ranges, bf16 input: block g, thread f
template <int F>
__global__ void k_segmax_sorted_b(const unsigned short* __restrict__ H,
                                  const int* __restrict__ bounds, float* __restrict__ out) {
    int g = blockIdx.x;
    int f = threadIdx.x;
    int s = bounds[g], e = bounds[g + 1];
    float m = -INFINITY;
    for (int r = s; r < e; ++r)
        m = fmaxf(m, __uint_as_float(((unsigned)H[(size_t)r * F + f]) << 16));
    out[(size_t)g * F + f] = m;
}

// narrow fp32 GEMM NC=32, W staged in LDS
__global__ __launch_bounds__(256) void k_gemm_n32(const float* __restrict__ A,
                                                  const float* __restrict__ W,
                                                  const float* __restrict__ bias,
                                                  float* __restrict__ C, int M, int K) {
    __shared__ float Ws[128 * 32];
    int tid = threadIdx.x;
    for (int i = tid; i < K * 32; i += 256) Ws[i] = W[i];
    __syncthreads();
    int row = blockIdx.x * 8 + (tid >> 5);
    int col = tid & 31;
    if (row >= M) return;
    float acc = bias[col];
    const float* a = &A[(size_t)row * K];
    for (int k = 0; k < K; ++k) acc = fmaf(a[k], Ws[k * 32 + col], acc);
    C[(size_t)row * 32 + col] = acc;
}

// per-graph: z = Z[r,:32] @ W5 + b5, max over graph rows
__global__ __launch_bounds__(320) void k_z5_segmax(const float* __restrict__ Z,
        const float* __restrict__ W, const float* __restrict__ bias,
        const int* __restrict__ bounds, float* __restrict__ out) {
    __shared__ float Ws[320];
    __shared__ float red[320];
    int t = threadIdx.x;
    Ws[t] = W[t];
    __syncthreads();
    int g = blockIdx.x;
    int col = t % 10, rs = t / 10;
    float bcol = bias[col];
    int s = bounds[g], e = bounds[g + 1];
    float m = -INFINITY;
    for (int r = s + rs; r < e; r += 32) {
        float acc = bcol;
        const float* a = &Z[(size_t)r * 32];
#pragma unroll
        for (int k = 0; k < 32; ++k) acc = fmaf(a[k], Ws[k * 10 + col], acc);
        m = fmaxf(m, acc);
    }
    red[t] = m;
    __syncthreads();
    for (int step = 16; step >= 1; step >>= 1) {
        if (rs < step) red[rs * 10 + col] = fmaxf(red[rs * 10 + col], red[(rs + step) * 10 + col]);
        __syncthreads();
    }
    if (rs == 0) out[(size_t)g * 10 + col] = red[col];
}

extern "C" void kernel_launch(void* const* d_in, const int* in_sizes, int n_in,
                              void* d_out, int out_size, void* d_ws, size_t ws_size,
                              hipStream_t stream) {
    const float* x  = (const float*)d_in[0];
    const int* ei   = (const int*)d_in[1];
    const int* batch= (const int*)d_in[2];
    const float* W1 = (const float*)d_in[3];
    const float* b1 = (const float*)d_in[4];
    const float* W2 = (const float*)d_in[5];
    const float* b2 = (const float*)d_in[6];
    const float* W3 = (const float*)d_in[7];
    const float* b3 = (const float*)d_in[8];
    const float* W4 = (const float*)d_in[9];
    const float* b4 = (const float*)d_in[10];
    const float* W5 = (const float*)d_in[11];
    const float* b5 = (const float*)d_in[12];

    const int N  = in_sizes[2];           // 50000
    const int F  = in_sizes[0] / N;       // 128
    const int E  = in_sizes[1] / 2;       // 400000
    const int C1 = in_sizes[4];           // 512
    const int C2 = in_sizes[6];           // 256
    const int C3 = in_sizes[8];           // 128
    const int C5 = in_sizes[12];          // 10
    const int G  = out_size / (C2 + C5);  // 512
    const int NB = DIV_UP(N, 1024);       // scan blocks

    const int* srcp = ei;
    const int* dstp = ei + E;

    // ---- workspace layout (256B-aligned carve-outs) ----
    uintptr_t p = (uintptr_t)d_ws;
    auto carve = [&](size_t bytes) {
        uintptr_t r = p;
        p += (bytes + 255) & ~(size_t)255;
        return (void*)r;
    };
    int* hist    = (int*)carve(sizeof(int) * N);
    int* row_off = (int*)carve(sizeof(int) * (N + 1));
    int* cursor  = (int*)carve(sizeof(int) * N);
    int* bounds  = (int*)carve(sizeof(int) * (G + 1));
    int* bsum    = (int*)carve(sizeof(int) * NB);
    int* boff    = (int*)carve(sizeof(int) * NB);
    int* csr_src = (int*)carve(sizeof(int) * E);
    float* csr_w = (float*)carve(sizeof(float) * E);
    float* dinv  = (float*)carve(sizeof(float) * N);
    unsigned short* w1t = (unsigned short*)carve(sizeof(short) * F * C1);
    unsigned short* w2t = (unsigned short*)carve(sizeof(short) * C1 * C2);
    unsigned short* w3t = (unsigned short*)carve(sizeof(short) * C2 * C3);
    unsigned short* xb    = (unsigned short*)carve(sizeof(short) * (size_t)N * F);
    unsigned short* aggxb = (unsigned short*)carve(sizeof(short) * (size_t)N * F);
    unsigned short* h1b   = (unsigned short*)carve(sizeof(short) * (size_t)N * C1);
    unsigned short* t2b   = (unsigned short*)carve(sizeof(short) * (size_t)N * C2); // reused as z4
    unsigned short* h2b   = (unsigned short*)carve(sizeof(short) * (size_t)N * C2);
    float* z3 = (float*)carve(sizeof(float) * (size_t)N * C3);
    float* z4 = (float*)t2b;

    float* out     = (float*)d_out;
    float* out_emb = out + (size_t)G * C5;

    // ---- CSR build + dinv + graph bounds ----
    k_zero_i<<<DIV_UP(N, 256), 256, 0, stream>>>(hist, N);
    k_zero_i<<<DIV_UP(N, 256), 256, 0, stream>>>(cursor, N);
    k_hist<<<DIV_UP(E, 256), 256, 0, stream>>>(dstp, hist, E);
    k_scan_bsum<<<NB, 256, 0, stream>>>(hist, bsum, N);
    k_scan_boff<<<1, 1024, 0, stream>>>(bsum, boff, row_off, NB, N);
    k_scan_apply<<<NB, 256, 0, stream>>>(hist, boff, row_off, N);
    k_dinv<<<DIV_UP(N, 256), 256, 0, stream>>>(hist, dinv, N);
    k_bin<<<DIV_UP(E, 256), 256, 0, stream>>>(srcp, dstp, row_off, cursor, dinv,
                                              csr_src, csr_w, E);
    k_bounds<<<DIV_UP(G + 1, 256), 256, 0, stream>>>(batch, bounds, N, G);

    // ---- bf16 conversions ----
    k_f2b4<<<DIV_UP(N * F / 4, 256), 256, 0, stream>>>(x, xb, N * F / 4);
    k_wt<<<DIV_UP(F * C1, 256), 256, 0, stream>>>(W1, w1t, F, C1);
    k_wt<<<DIV_UP(C1 * C2, 256), 256, 0, stream>>>(W2, w2t, C1, C2);
    k_wt<<<DIV_UP(C2 * C3, 256), 256, 0, stream>>>(W3, w3t, C2, C3);

    // ---- layer 1: gather (bf16) -> MFMA GEMM + bias + leakyrelu -> h1 bf16 ----
    k_gather_b<128, 0, 1><<<DIV_UP(N, 16), 256, 0, stream>>>(
        xb, row_off, csr_src, csr_w, dinv, nullptr, nullptr, aggxb, N);
    dim3 g1(C1 / 128, DIV_UP(N, 128));
    k_gemm_mfma<1, 1><<<g1, 256, 0, stream>>>(aggxb, w1t, b1, h1b, N, F, C1);

    // ---- layer 2: MFMA GEMM -> t2 bf16 -> gather (+b2) -> h2 bf16 only ----
    dim3 g2(C2 / 128, DIV_UP(N, 128));
    k_gemm_mfma<1, 0><<<g2, 256, 0, stream>>>(h1b, w2t, nullptr, t2b, N, C1, C2);
    k_gather_b<256, 0, 1><<<DIV_UP(N, 8), 256, 0, stream>>>(
        t2b, row_off, csr_src, csr_w, dinv, b2, nullptr, h2b, N);

    // ---- embs = segment_max(h2 bf16) ----
    k_segmax_sorted_b<256><<<G, 256, 0, stream>>>(h2b, bounds, out_emb);

    // ---- MLP head: MFMA L3 (fp32 out) -> fp32 n32 -> fused z5+segmax ----
    dim3 g3(C3 / 128, DIV_UP(N, 128));
    k_gemm_mfma<0, 0><<<g3, 256, 0, stream>>>(h2b, w3t, b3, z3, N, C2, C3);
    k_gemm_n32<<<DIV_UP(N, 8), 256, 0, stream>>>(z3, W4, b4, z4, N, C3);
    k_z5_segmax<<<G, 320, 0, stream>>>(z4, W5, b5, bounds, out);
}

// Round 5
// 369.760 us; speedup vs baseline: 7.1086x; 1.0685x over previous
//
#include <hip/hip_runtime.h>
#include <math.h>

#define DIV_UP(a,b) (((a)+(b)-1)/(b))

typedef __attribute__((ext_vector_type(8))) short bf16x8;
typedef __attribute__((ext_vector_type(4))) float f32x4;

// fp32 -> bf16 round-to-nearest-even
__device__ inline unsigned short f2b(float x) {
    unsigned int u = __float_as_uint(x);
    u += 0x7fffu + ((u >> 16) & 1u);
    return (unsigned short)(u >> 16);
}

// 8 packed bf16 (uint4) -> 8 floats
__device__ inline void cvt8(uint4 v, float* a) {
    a[0] = __uint_as_float(v.x << 16); a[1] = __uint_as_float(v.x & 0xffff0000u);
    a[2] = __uint_as_float(v.y << 16); a[3] = __uint_as_float(v.y & 0xffff0000u);
    a[4] = __uint_as_float(v.z << 16); a[5] = __uint_as_float(v.z & 0xffff0000u);
    a[6] = __uint_as_float(v.w << 16); a[7] = __uint_as_float(v.w & 0xffff0000u);
}

__global__ void k_zero_i(int* p, int n) {
    int i = blockIdx.x * blockDim.x + threadIdx.x;
    if (i < n) p[i] = 0;
}

__global__ void k_hist(const int* __restrict__ dst, int* __restrict__ hist, int E) {
    int i = blockIdx.x * blockDim.x + threadIdx.x;
    if (i < E) atomicAdd(&hist[dst[i]], 1);
}

__global__ void k_dinv(const int* __restrict__ hist, float* __restrict__ dinv, int n) {
    int i = blockIdx.x * blockDim.x + threadIdx.x;
    if (i < n) dinv[i] = rsqrtf((float)(hist[i] + 1));
}

// ---- hierarchical scan: 1024 elements per block ----
__global__ __launch_bounds__(256) void k_scan_bsum(const int* __restrict__ hist,
                                                   int* __restrict__ bsum, int N) {
    __shared__ int red[256];
    int t = threadIdx.x;
    int base = blockIdx.x * 1024 + t * 4;
    int s = 0;
    if (base + 3 < N) {
        int4 v = *(const int4*)&hist[base];
        s = v.x + v.y + v.z + v.w;
    } else {
        for (int j = 0; j < 4; ++j) if (base + j < N) s += hist[base + j];
    }
    red[t] = s;
    __syncthreads();
    for (int off = 128; off >= 1; off >>= 1) {
        if (t < off) red[t] += red[t + off];
        __syncthreads();
    }
    if (t == 0) bsum[blockIdx.x] = red[0];
}

// single block scans NB (<=1024) block sums -> exclusive boff; writes row_off[N]=total
__global__ __launch_bounds__(1024) void k_scan_boff(const int* __restrict__ bsum,
        int* __restrict__ boff, int* __restrict__ row_off, int NB, int N) {
    __shared__ int s[1024];
    int t = threadIdx.x;
    int v = (t < NB) ? bsum[t] : 0;
    s[t] = v;
    __syncthreads();
    for (int off = 1; off < 1024; off <<= 1) {
        int u = (t >= off) ? s[t - off] : 0;
        __syncthreads();
        s[t] += u;
        __syncthreads();
    }
    if (t < NB) boff[t] = s[t] - v;
    if (t == NB - 1) row_off[N] = s[t];
}

__global__ __launch_bounds__(256) void k_scan_apply(const int* __restrict__ hist,
        const int* __restrict__ boff, int* __restrict__ row_off, int N) {
    __shared__ int s[256];
    int t = threadIdx.x;
    int base = blockIdx.x * 1024 + t * 4;
    int v[4];
    int loc = 0;
#pragma unroll
    for (int j = 0; j < 4; ++j) { v[j] = (base + j < N) ? hist[base + j] : 0; loc += v[j]; }
    s[t] = loc;
    __syncthreads();
    for (int off = 1; off < 256; off <<= 1) {
        int u = (t >= off) ? s[t - off] : 0;
        __syncthreads();
        s[t] += u;
        __syncthreads();
    }
    int run = boff[blockIdx.x] + s[t] - loc;
#pragma unroll
    for (int j = 0; j < 4; ++j) {
        if (base + j < N) row_off[base + j] = run;
        run += v[j];
    }
}

__global__ void k_bin(const int* __restrict__ src, const int* __restrict__ dst,
                      const int* __restrict__ row_off, int* __restrict__ cursor,
                      const float* __restrict__ dinv,
                      int* __restrict__ csr_src, float* __restrict__ csr_w, int E) {
    int i = blockIdx.x * blockDim.x + threadIdx.x;
    if (i >= E) return;
    int d = dst[i], s = src[i];
    int pos = row_off[d] + atomicAdd(&cursor[d], 1);
    csr_src[pos] = s;
    csr_w[pos] = dinv[s] * dinv[d];
}

__global__ void k_bounds(const int* __restrict__ batch, int* __restrict__ bounds,
                         int N, int G) {
    int g = blockIdx.x * blockDim.x + threadIdx.x;
    if (g > G) return;
    int lo = 0, hi = N;
    while (lo < hi) { int mid = (lo + hi) >> 1; if (batch[mid] < g) lo = mid + 1; else hi = mid; }
    bounds[g] = lo;
}

// fp32[4] -> bf16[4] elementwise convert
__global__ void k_f2b4(const float* __restrict__ in, unsigned short* __restrict__ out, int n4) {
    int i = blockIdx.x * blockDim.x + threadIdx.x;
    if (i >= n4) return;
    float4 v = ((const float4*)in)[i];
    ushort4 o;
    o.x = f2b(v.x); o.y = f2b(v.y); o.z = f2b(v.z); o.w = f2b(v.w);
    ((ushort4*)out)[i] = o;
}

// weight transpose+convert: out_bf16[n*K + k] = in[k*NC + n]
__global__ void k_wt(const float* __restrict__ in, unsigned short* __restrict__ out,
                     int K, int NC) {
    int i = blockIdx.x * blockDim.x + threadIdx.x;
    if (i >= K * NC) return;
    int k = i / NC, n = i % NC;
    out[(size_t)n * K + k] = f2b(in[i]);
}

// gather-aggregate over dst-CSR, bf16 in, optional fp32 and/or bf16 out.
template <int F, int WF32, int WB16>
__global__ __launch_bounds__(256) void k_gather_b(const unsigned short* __restrict__ H,
        const int* __restrict__ row_off, const int* __restrict__ csr_src,
        const float* __restrict__ csr_w, const float* __restrict__ dinv,
        const float* __restrict__ bias, float* __restrict__ outf,
        unsigned short* __restrict__ outb, int N) {
    const int LPN = F / 8;
    const int NPB = 256 / LPN;
    int node = blockIdx.x * NPB + threadIdx.x / LPN;
    if (node >= N) return;
    int f = (threadIdx.x % LPN) * 8;
    float sc = dinv[node]; sc *= sc;
    float a[8];
    cvt8(*(const uint4*)&H[(size_t)node * F + f], a);
#pragma unroll
    for (int j = 0; j < 8; ++j) a[j] *= sc;
    if (bias) {
#pragma unroll
        for (int j = 0; j < 8; ++j) a[j] += bias[f + j];
    }
    int e0 = row_off[node], e1 = row_off[node + 1];
    for (int e = e0; e < e1; ++e) {
        int s = csr_src[e];
        float w = csr_w[e];
        float b[8];
        cvt8(*(const uint4*)&H[(size_t)s * F + f], b);
#pragma unroll
        for (int j = 0; j < 8; ++j) a[j] = fmaf(w, b[j], a[j]);
    }
    if (WF32) {
        *(float4*)&outf[(size_t)node * F + f] = make_float4(a[0], a[1], a[2], a[3]);
        *(float4*)&outf[(size_t)node * F + f + 4] = make_float4(a[4], a[5], a[6], a[7]);
    }
    if (WB16) {
        uint4 o;
        o.x = (unsigned)f2b(a[0]) | ((unsigned)f2b(a[1]) << 16);
        o.y = (unsigned)f2b(a[2]) | ((unsigned)f2b(a[3]) << 16);
        o.z = (unsigned)f2b(a[4]) | ((unsigned)f2b(a[5]) << 16);
        o.w = (unsigned)f2b(a[6]) | ((unsigned)f2b(a[7]) << 16);
        *(uint4*)&outb[(size_t)node * F + f] = o;
    }
}

// bf16 MFMA GEMM: C[M,NC] = act(A[M,K] @ B[K,NC] + bias)
// A bf16 row-major [M,K]; Bt bf16 TRANSPOSED [NC,K]. 128x128 tile, BK=32,
// 4 waves (2x2), each wave 64x64 via 4x4 grid of 16x16x32 MFMAs.
// OPERAND-SWAP: mfma(bfv, afv) -> transposed fragment: lane holds one row
// (m = lane&15) and 4 CONTIGUOUS cols ((lane>>4)*4 + reg) => vector epilogue.
template <int OUT_BF16, int ACT>
__global__ __launch_bounds__(256) void k_gemm_mfma(const unsigned short* __restrict__ A,
        const unsigned short* __restrict__ Bt, const float* __restrict__ bias,
        void* __restrict__ Cout, int M, int K, int NC) {
    __shared__ __align__(16) unsigned short As[128][40];
    __shared__ __align__(16) unsigned short Bs[128][40];
    int tid = threadIdx.x;
    int wave = tid >> 6, lane = tid & 63;
    int row0 = blockIdx.y * 128, col0 = blockIdx.x * 128;
    int wr = (wave >> 1) * 64, wc = (wave & 1) * 64;
    f32x4 acc[4][4] = {};
    int sr = tid >> 2;
    int sk = (tid & 3) * 8;
    int lr = lane & 15;
    int lq = (lane >> 4) * 8;

    for (int k0 = 0; k0 < K; k0 += 32) {
#pragma unroll
        for (int i = 0; i < 2; ++i) {
            int r = sr + i * 64;
            int gr = min(row0 + r, M - 1);
            *(uint4*)&As[r][sk] = *(const uint4*)&A[(size_t)gr * K + k0 + sk];
            *(uint4*)&Bs[r][sk] = *(const uint4*)&Bt[(size_t)(col0 + r) * K + k0 + sk];
        }
        __syncthreads();
        bf16x8 af[4], bfv[4];
#pragma unroll
        for (int i = 0; i < 4; ++i) af[i] = *(const bf16x8*)&As[wr + i * 16 + lr][lq];
#pragma unroll
        for (int j = 0; j < 4; ++j) bfv[j] = *(const bf16x8*)&Bs[wc + j * 16 + lr][lq];
#pragma unroll
        for (int i = 0; i < 4; ++i)
#pragma unroll
            for (int j = 0; j < 4; ++j)
                acc[i][j] = __builtin_amdgcn_mfma_f32_16x16x32_bf16(bfv[j], af[i], acc[i][j], 0, 0, 0);
        __syncthreads();
    }

    // Epilogue: lane owns row m=lane&15 of each i-block, cols q4..q4+3 of each j-block.
    int q4 = (lane >> 4) * 4;
    float4 bb[4];
#pragma unroll
    for (int j = 0; j < 4; ++j)
        bb[j] = bias ? *(const float4*)&bias[col0 + wc + j * 16 + q4]
                     : make_float4(0.f, 0.f, 0.f, 0.f);
#pragma unroll
    for (int i = 0; i < 4; ++i) {
        int row = row0 + wr + i * 16 + lr;
        if (row >= M) continue;
#pragma unroll
        for (int j = 0; j < 4; ++j) {
            int c0 = col0 + wc + j * 16 + q4;
            float4 v;
            v.x = acc[i][j][0] + bb[j].x;
            v.y = acc[i][j][1] + bb[j].y;
            v.z = acc[i][j][2] + bb[j].z;
            v.w = acc[i][j][3] + bb[j].w;
            if (ACT) {
                v.x = (v.x >= 0.f) ? v.x : 0.01f * v.x;
                v.y = (v.y >= 0.f) ? v.y : 0.01f * v.y;
                v.z = (v.z >= 0.f) ? v.z : 0.01f * v.z;
                v.w = (v.w >= 0.f) ? v.w : 0.01f * v.w;
            }
            if (OUT_BF16) {
                uint2 o;
                o.x = (unsigned)f2b(v.x) | ((unsigned)f2b(v.y) << 16);
                o.y = (unsigned)f2b(v.z) | ((unsigned)f2b(v.w) << 16);
                *(uint2*)&((unsigned short*)Cout)[(size_t)row * NC + c0] = o;
            } else {
                *(float4*)&((float*)Cout)[(size_t)row * NC + c0] = v;
            }
        }
    }
}

// segment_max over sorted ranges, bf16 input: block g, thread f
template <int F>
__global__ void k_segmax_sorted_b(const unsigned short* __restrict__ H,
                                  const int* __restrict__ bounds, float* __restrict__ out) {
    int g = blockIdx.x;
    int f = threadIdx.x;
    int s = bounds[g], e = bounds[g + 1];
    float m = -INFINITY;
    for (int r = s; r < e; ++r)
        m = fmaxf(m, __uint_as_float(((unsigned)H[(size_t)r * F + f]) << 16));
    out[(size_t)g * F + f] = m;
}

// narrow fp32 GEMM NC=32, W staged in LDS
__global__ __launch_bounds__(256) void k_gemm_n32(const float* __restrict__ A,
                                                  const float* __restrict__ W,
                                                  const float* __restrict__ bias,
                                                  float* __restrict__ C, int M, int K) {
    __shared__ float Ws[128 * 32];
    int tid = threadIdx.x;
    for (int i = tid; i < K * 32; i += 256) Ws[i] = W[i];
    __syncthreads();
    int row = blockIdx.x * 8 + (tid >> 5);
    int col = tid & 31;
    if (row >= M) return;
    float acc = bias[col];
    const float* a = &A[(size_t)row * K];
    for (int k = 0; k < K; ++k) acc = fmaf(a[k], Ws[k * 32 + col], acc);
    C[(size_t)row * 32 + col] = acc;
}

// per-graph: z = Z[r,:32] @ W5 + b5, max over graph rows
__global__ __launch_bounds__(320) void k_z5_segmax(const float* __restrict__ Z,
        const float* __restrict__ W, const float* __restrict__ bias,
        const int* __restrict__ bounds, float* __restrict__ out) {
    __shared__ float Ws[320];
    __shared__ float red[320];
    int t = threadIdx.x;
    Ws[t] = W[t];
    __syncthreads();
    int g = blockIdx.x;
    int col = t % 10, rs = t / 10;
    float bcol = bias[col];
    int s = bounds[g], e = bounds[g + 1];
    float m = -INFINITY;
    for (int r = s + rs; r < e; r += 32) {
        float acc = bcol;
        const float* a = &Z[(size_t)r * 32];
#pragma unroll
        for (int k = 0; k < 32; ++k) acc = fmaf(a[k], Ws[k * 10 + col], acc);
        m = fmaxf(m, acc);
    }
    red[t] = m;
    __syncthreads();
    for (int step = 16; step >= 1; step >>= 1) {
        if (rs < step) red[rs * 10 + col] = fmaxf(red[rs * 10 + col], red[(rs + step) * 10 + col]);
        __syncthreads();
    }
    if (rs == 0) out[(size_t)g * 10 + col] = red[col];
}

extern "C" void kernel_launch(void* const* d_in, const int* in_sizes, int n_in,
                              void* d_out, int out_size, void* d_ws, size_t ws_size,
                              hipStream_t stream) {
    const float* x  = (const float*)d_in[0];
    const int* ei   = (const int*)d_in[1];
    const int* batch= (const int*)d_in[2];
    const float* W1 = (const float*)d_in[3];
    const float* b1 = (const float*)d_in[4];
    const float* W2 = (const float*)d_in[5];
    const float* b2 = (const float*)d_in[6];
    const float* W3 = (const float*)d_in[7];
    const float* b3 = (const float*)d_in[8];
    const float* W4 = (const float*)d_in[9];
    const float* b4 = (const float*)d_in[10];
    const float* W5 = (const float*)d_in[11];
    const float* b5 = (const float*)d_in[12];

    const int N  = in_sizes[2];           // 50000
    const int F  = in_sizes[0] / N;       // 128
    const int E  = in_sizes[1] / 2;       // 400000
    const int C1 = in_sizes[4];           // 512
    const int C2 = in_sizes[6];           // 256
    const int C3 = in_sizes[8];           // 128
    const int C5 = in_sizes[12];          // 10
    const int G  = out_size / (C2 + C5);  // 512
    const int NB = DIV_UP(N, 1024);

    const int* srcp = ei;
    const int* dstp = ei + E;

    // ---- workspace layout (256B-aligned carve-outs) ----
    uintptr_t p = (uintptr_t)d_ws;
    auto carve = [&](size_t bytes) {
        uintptr_t r = p;
        p += (bytes + 255) & ~(size_t)255;
        return (void*)r;
    };
    int* hist    = (int*)carve(sizeof(int) * N);
    int* row_off = (int*)carve(sizeof(int) * (N + 1));
    int* cursor  = (int*)carve(sizeof(int) * N);
    int* bounds  = (int*)carve(sizeof(int) * (G + 1));
    int* bsum    = (int*)carve(sizeof(int) * NB);
    int* boff    = (int*)carve(sizeof(int) * NB);
    int* csr_src = (int*)carve(sizeof(int) * E);
    float* csr_w = (float*)carve(sizeof(float) * E);
    float* dinv  = (float*)carve(sizeof(float) * N);
    unsigned short* w1t = (unsigned short*)carve(sizeof(short) * F * C1);
    unsigned short* w2t = (unsigned short*)carve(sizeof(short) * C1 * C2);
    unsigned short* w3t = (unsigned short*)carve(sizeof(short) * C2 * C3);
    unsigned short* xb    = (unsigned short*)carve(sizeof(short) * (size_t)N * F);
    unsigned short* aggxb = (unsigned short*)carve(sizeof(short) * (size_t)N * F);
    unsigned short* h1b   = (unsigned short*)carve(sizeof(short) * (size_t)N * C1);
    unsigned short* t2b   = (unsigned short*)carve(sizeof(short) * (size_t)N * C2); // reused as z4
    unsigned short* h2b   = (unsigned short*)carve(sizeof(short) * (size_t)N * C2);
    float* z3 = (float*)carve(sizeof(float) * (size_t)N * C3);
    float* z4 = (float*)t2b;

    float* out     = (float*)d_out;
    float* out_emb = out + (size_t)G * C5;

    // ---- CSR build + dinv + graph bounds ----
    k_zero_i<<<DIV_UP(N, 256), 256, 0, stream>>>(hist, N);
    k_zero_i<<<DIV_UP(N, 256), 256, 0, stream>>>(cursor, N);
    k_hist<<<DIV_UP(E, 256), 256, 0, stream>>>(dstp, hist, E);
    k_scan_bsum<<<NB, 256, 0, stream>>>(hist, bsum, N);
    k_scan_boff<<<1, 1024, 0, stream>>>(bsum, boff, row_off, NB, N);
    k_scan_apply<<<NB, 256, 0, stream>>>(hist, boff, row_off, N);
    k_dinv<<<DIV_UP(N, 256), 256, 0, stream>>>(hist, dinv, N);
    k_bin<<<DIV_UP(E, 256), 256, 0, stream>>>(srcp, dstp, row_off, cursor, dinv,
                                              csr_src, csr_w, E);
    k_bounds<<<DIV_UP(G + 1, 256), 256, 0, stream>>>(batch, bounds, N, G);

    // ---- bf16 conversions ----
    k_f2b4<<<DIV_UP(N * F / 4, 256), 256, 0, stream>>>(x, xb, N * F / 4);
    k_wt<<<DIV_UP(F * C1, 256), 256, 0, stream>>>(W1, w1t, F, C1);
    k_wt<<<DIV_UP(C1 * C2, 256), 256, 0, stream>>>(W2, w2t, C1, C2);
    k_wt<<<DIV_UP(C2 * C3, 256), 256, 0, stream>>>(W3, w3t, C2, C3);

    // ---- layer 1: gather (bf16) -> MFMA GEMM + bias + leakyrelu -> h1 bf16 ----
    k_gather_b<128, 0, 1><<<DIV_UP(N, 16), 256, 0, stream>>>(
        xb, row_off, csr_src, csr_w, dinv, nullptr, nullptr, aggxb, N);
    dim3 g1(C1 / 128, DIV_UP(N, 128));
    k_gemm_mfma<1, 1><<<g1, 256, 0, stream>>>(aggxb, w1t, b1, h1b, N, F, C1);

    // ---- layer 2: MFMA GEMM -> t2 bf16 -> gather (+b2) -> h2 bf16 only ----
    dim3 g2(C2 / 128, DIV_UP(N, 128));
    k_gemm_mfma<1, 0><<<g2, 256, 0, stream>>>(h1b, w2t, nullptr, t2b, N, C1, C2);
    k_gather_b<256, 0, 1><<<DIV_UP(N, 8), 256, 0, stream>>>(
        t2b, row_off, csr_src, csr_w, dinv, b2, nullptr, h2b, N);

    // ---- embs = segment_max(h2 bf16) ----
    k_segmax_sorted_b<256><<<G, 256, 0, stream>>>(h2b, bounds, out_emb);

    // ---- MLP head: MFMA L3 (fp32 out) -> fp32 n32 -> fused z5+segmax ----
    dim3 g3(C3 / 128, DIV_UP(N, 128));
    k_gemm_mfma<0, 0><<<g3, 256, 0, stream>>>(h2b, w3t, b3, z3, N, C2, C3);
    k_gemm_n32<<<DIV_UP(N, 8), 256, 0, stream>>>(z3, W4, b4, z4, N, C3);
    k_z5_segmax<<<G, 320, 0, stream>>>(z4, W5, b5, bounds, out);
}

// Round 6
// 365.852 us; speedup vs baseline: 7.1846x; 1.0107x over previous
//
#include <hip/hip_runtime.h>
#include <math.h>

#define DIV_UP(a,b) (((a)+(b)-1)/(b))

typedef __attribute__((ext_vector_type(8))) short bf16x8;
typedef __attribute__((ext_vector_type(4))) float f32x4;

// fp32 -> bf16 round-to-nearest-even
__device__ inline unsigned short f2b(float x) {
    unsigned int u = __float_as_uint(x);
    u += 0x7fffu + ((u >> 16) & 1u);
    return (unsigned short)(u >> 16);
}

// 8 packed bf16 (uint4) -> 8 floats
__device__ inline void cvt8(uint4 v, float* a) {
    a[0] = __uint_as_float(v.x << 16); a[1] = __uint_as_float(v.x & 0xffff0000u);
    a[2] = __uint_as_float(v.y << 16); a[3] = __uint_as_float(v.y & 0xffff0000u);
    a[4] = __uint_as_float(v.z << 16); a[5] = __uint_as_float(v.z & 0xffff0000u);
    a[6] = __uint_as_float(v.w << 16); a[7] = __uint_as_float(v.w & 0xffff0000u);
}

// async global->LDS 16B: per-lane global addr, LDS dest = wave-uniform base + lane*16
__device__ inline void gl16(void* lds, const void* g) {
    __builtin_amdgcn_global_load_lds(
        (const __attribute__((address_space(1))) void*)g,
        (__attribute__((address_space(3))) void*)lds, 16, 0, 0);
}

__global__ void k_zero_i(int* p, int n) {
    int i = blockIdx.x * blockDim.x + threadIdx.x;
    if (i < n) p[i] = 0;
}

__global__ void k_hist(const int* __restrict__ dst, int* __restrict__ hist, int E) {
    int i = blockIdx.x * blockDim.x + threadIdx.x;
    if (i < E) atomicAdd(&hist[dst[i]], 1);
}

__global__ void k_dinv(const int* __restrict__ hist, float* __restrict__ dinv, int n) {
    int i = blockIdx.x * blockDim.x + threadIdx.x;
    if (i < n) dinv[i] = rsqrtf((float)(hist[i] + 1));
}

// ---- hierarchical scan: 1024 elements per block ----
__global__ __launch_bounds__(256) void k_scan_bsum(const int* __restrict__ hist,
                                                   int* __restrict__ bsum, int N) {
    __shared__ int red[256];
    int t = threadIdx.x;
    int base = blockIdx.x * 1024 + t * 4;
    int s = 0;
    if (base + 3 < N) {
        int4 v = *(const int4*)&hist[base];
        s = v.x + v.y + v.z + v.w;
    } else {
        for (int j = 0; j < 4; ++j) if (base + j < N) s += hist[base + j];
    }
    red[t] = s;
    __syncthreads();
    for (int off = 128; off >= 1; off >>= 1) {
        if (t < off) red[t] += red[t + off];
        __syncthreads();
    }
    if (t == 0) bsum[blockIdx.x] = red[0];
}

__global__ __launch_bounds__(1024) void k_scan_boff(const int* __restrict__ bsum,
        int* __restrict__ boff, int* __restrict__ row_off, int NB, int N) {
    __shared__ int s[1024];
    int t = threadIdx.x;
    int v = (t < NB) ? bsum[t] : 0;
    s[t] = v;
    __syncthreads();
    for (int off = 1; off < 1024; off <<= 1) {
        int u = (t >= off) ? s[t - off] : 0;
        __syncthreads();
        s[t] += u;
        __syncthreads();
    }
    if (t < NB) boff[t] = s[t] - v;
    if (t == NB - 1) row_off[N] = s[t];
}

__global__ __launch_bounds__(256) void k_scan_apply(const int* __restrict__ hist,
        const int* __restrict__ boff, int* __restrict__ row_off, int N) {
    __shared__ int s[256];
    int t = threadIdx.x;
    int base = blockIdx.x * 1024 + t * 4;
    int v[4];
    int loc = 0;
#pragma unroll
    for (int j = 0; j < 4; ++j) { v[j] = (base + j < N) ? hist[base + j] : 0; loc += v[j]; }
    s[t] = loc;
    __syncthreads();
    for (int off = 1; off < 256; off <<= 1) {
        int u = (t >= off) ? s[t - off] : 0;
        __syncthreads();
        s[t] += u;
        __syncthreads();
    }
    int run = boff[blockIdx.x] + s[t] - loc;
#pragma unroll
    for (int j = 0; j < 4; ++j) {
        if (base + j < N) row_off[base + j] = run;
        run += v[j];
    }
}

__global__ void k_bin(const int* __restrict__ src, const int* __restrict__ dst,
                      const int* __restrict__ row_off, int* __restrict__ cursor,
                      const float* __restrict__ dinv,
                      int* __restrict__ csr_src, float* __restrict__ csr_w, int E) {
    int i = blockIdx.x * blockDim.x + threadIdx.x;
    if (i >= E) return;
    int d = dst[i], s = src[i];
    int pos = row_off[d] + atomicAdd(&cursor[d], 1);
    csr_src[pos] = s;
    csr_w[pos] = dinv[s] * dinv[d];
}

__global__ void k_bounds(const int* __restrict__ batch, int* __restrict__ bounds,
                         int N, int G) {
    int g = blockIdx.x * blockDim.x + threadIdx.x;
    if (g > G) return;
    int lo = 0, hi = N;
    while (lo < hi) { int mid = (lo + hi) >> 1; if (batch[mid] < g) lo = mid + 1; else hi = mid; }
    bounds[g] = lo;
}

// fp32[4] -> bf16[4] elementwise convert
__global__ void k_f2b4(const float* __restrict__ in, unsigned short* __restrict__ out, int n4) {
    int i = blockIdx.x * blockDim.x + threadIdx.x;
    if (i >= n4) return;
    float4 v = ((const float4*)in)[i];
    ushort4 o;
    o.x = f2b(v.x); o.y = f2b(v.y); o.z = f2b(v.z); o.w = f2b(v.w);
    ((ushort4*)out)[i] = o;
}

// weight transpose+convert: out_bf16[n*K + k] = in[k*NC + n]
__global__ void k_wt(const float* __restrict__ in, unsigned short* __restrict__ out,
                     int K, int NC) {
    int i = blockIdx.x * blockDim.x + threadIdx.x;
    if (i >= K * NC) return;
    int k = i / NC, n = i % NC;
    out[(size_t)n * K + k] = f2b(in[i]);
}

// gather-aggregate over dst-CSR, bf16 in, optional fp32 and/or bf16 out.
template <int F, int WF32, int WB16>
__global__ __launch_bounds__(256) void k_gather_b(const unsigned short* __restrict__ H,
        const int* __restrict__ row_off, const int* __restrict__ csr_src,
        const float* __restrict__ csr_w, const float* __restrict__ dinv,
        const float* __restrict__ bias, float* __restrict__ outf,
        unsigned short* __restrict__ outb, int N) {
    const int LPN = F / 8;
    const int NPB = 256 / LPN;
    int node = blockIdx.x * NPB + threadIdx.x / LPN;
    if (node >= N) return;
    int f = (threadIdx.x % LPN) * 8;
    float sc = dinv[node]; sc *= sc;
    float a[8];
    cvt8(*(const uint4*)&H[(size_t)node * F + f], a);
#pragma unroll
    for (int j = 0; j < 8; ++j) a[j] *= sc;
    if (bias) {
#pragma unroll
        for (int j = 0; j < 8; ++j) a[j] += bias[f + j];
    }
    int e0 = row_off[node], e1 = row_off[node + 1];
    for (int e = e0; e < e1; ++e) {
        int s = csr_src[e];
        float w = csr_w[e];
        float b[8];
        cvt8(*(const uint4*)&H[(size_t)s * F + f], b);
#pragma unroll
        for (int j = 0; j < 8; ++j) a[j] = fmaf(w, b[j], a[j]);
    }
    if (WF32) {
        *(float4*)&outf[(size_t)node * F + f] = make_float4(a[0], a[1], a[2], a[3]);
        *(float4*)&outf[(size_t)node * F + f + 4] = make_float4(a[4], a[5], a[6], a[7]);
    }
    if (WB16) {
        uint4 o;
        o.x = (unsigned)f2b(a[0]) | ((unsigned)f2b(a[1]) << 16);
        o.y = (unsigned)f2b(a[2]) | ((unsigned)f2b(a[3]) << 16);
        o.z = (unsigned)f2b(a[4]) | ((unsigned)f2b(a[5]) << 16);
        o.w = (unsigned)f2b(a[6]) | ((unsigned)f2b(a[7]) << 16);
        *(uint4*)&outb[(size_t)node * F + f] = o;
    }
}

// bf16 MFMA GEMM: C[M,NC] = act(A[M,K] @ B[K,NC] + bias)
// A bf16 row-major [M,K]; Bt bf16 TRANSPOSED [NC,K]. 128x128 tile, BK=64,
// 4 waves (2x2), each wave 64x64 via 4x4x(2 k-steps) of 16x16x32 MFMAs.
// Staging: global_load_lds width=16 (no VGPR round-trip). LDS rows are
// XOR-swizzled (16B chunk c of row r holds global chunk c^(r&7)) so the
// unpadded [128][64] layout has only free 2-way aliasing on ds_read_b128.
// Operand-swap mfma(bv, af): lane owns row m=lane&15, 4 contiguous cols.
template <int OUT_BF16, int ACT>
__global__ __launch_bounds__(256) void k_gemm_mfma(const unsigned short* __restrict__ A,
        const unsigned short* __restrict__ Bt, const float* __restrict__ bias,
        void* __restrict__ Cout, int M, int K, int NC) {
    __shared__ __align__(16) unsigned short As[128][64];   // 16 KB
    __shared__ __align__(16) unsigned short Bs[128][64];   // 16 KB
    int tid = threadIdx.x;
    int wave = tid >> 6, lane = tid & 63;
    int row0 = blockIdx.y * 128, col0 = blockIdx.x * 128;
    int wr = (wave >> 1) * 64, wc = (wave & 1) * 64;
    f32x4 acc[4][4] = {};
    int lr = lane & 15;
    int lg = lane >> 4;                      // k-group 0..3
    int sw = ((lane & 7) ^ (lane >> 3)) << 3;   // staging: swizzled hw offset in row (lane-const)
    int ch0 = ((lg) ^ (lr & 7)) << 3;        // fragment chunk, k-step 0
    int ch1 = ch0 ^ (4 << 3);                // k-step 1 (bit-4 flip of chunk idx)

    for (int k0 = 0; k0 < K; k0 += 64) {
#pragma unroll
        for (int c = 0; c < 4; ++c) {
            int rl = wave * 32 + c * 8 + (lane >> 3);   // local row this lane stages
            int gr = min(row0 + rl, M - 1);             // clamp; OOB rows never stored
            gl16(&As[wave * 32 + c * 8][0], &A[(size_t)gr * K + k0 + sw]);
            gl16(&Bs[wave * 32 + c * 8][0], &Bt[(size_t)(col0 + rl) * K + k0 + sw]);
        }
        __syncthreads();
        bf16x8 af[2][4], bv[2][4];
#pragma unroll
        for (int i = 0; i < 4; ++i) {
            int ra = wr + i * 16 + lr;
            int rb = wc + i * 16 + lr;
            af[0][i] = *(const bf16x8*)&As[ra][ch0];
            af[1][i] = *(const bf16x8*)&As[ra][ch1];
            bv[0][i] = *(const bf16x8*)&Bs[rb][ch0];
            bv[1][i] = *(const bf16x8*)&Bs[rb][ch1];
        }
#pragma unroll
        for (int s = 0; s < 2; ++s)
#pragma unroll
            for (int i = 0; i < 4; ++i)
#pragma unroll
                for (int j = 0; j < 4; ++j)
                    acc[i][j] = __builtin_amdgcn_mfma_f32_16x16x32_bf16(bv[s][j], af[s][i], acc[i][j], 0, 0, 0);
        __syncthreads();
    }

    // Epilogue: lane owns row m=lane&15 of each i-block, cols q4..q4+3 of each j-block.
    int q4 = lg * 4;
    float4 bb[4];
#pragma unroll
    for (int j = 0; j < 4; ++j)
        bb[j] = bias ? *(const float4*)&bias[col0 + wc + j * 16 + q4]
                     : make_float4(0.f, 0.f, 0.f, 0.f);
#pragma unroll
    for (int i = 0; i < 4; ++i) {
        int row = row0 + wr + i * 16 + lr;
        if (row >= M) continue;
#pragma unroll
        for (int j = 0; j < 4; ++j) {
            int c0 = col0 + wc + j * 16 + q4;
            float4 v;
            v.x = acc[i][j][0] + bb[j].x;
            v.y = acc[i][j][1] + bb[j].y;
            v.z = acc[i][j][2] + bb[j].z;
            v.w = acc[i][j][3] + bb[j].w;
            if (ACT) {
                v.x = (v.x >= 0.f) ? v.x : 0.01f * v.x;
                v.y = (v.y >= 0.f) ? v.y : 0.01f * v.y;
                v.z = (v.z >= 0.f) ? v.z : 0.01f * v.z;
                v.w = (v.w >= 0.f) ? v.w : 0.01f * v.w;
            }
            if (OUT_BF16) {
                uint2 o;
                o.x = (unsigned)f2b(v.x) | ((unsigned)f2b(v.y) << 16);
                o.y = (unsigned)f2b(v.z) | ((unsigned)f2b(v.w) << 16);
                *(uint2*)&((unsigned short*)Cout)[(size_t)row * NC + c0] = o;
            } else {
                *(float4*)&((float*)Cout)[(size_t)row * NC + c0] = v;
            }
        }
    }
}

// segment_max over sorted ranges, bf16 input: block g, thread f
template <int F>
__global__ void k_segmax_sorted_b(const unsigned short* __restrict__ H,
                                  const int* __restrict__ bounds, float* __restrict__ out) {
    int g = blockIdx.x;
    int f = threadIdx.x;
    int s = bounds[g], e = bounds[g + 1];
    float m = -INFINITY;
    for (int r = s; r < e; ++r)
        m = fmaxf(m, __uint_as_float(((unsigned)H[(size_t)r * F + f]) << 16));
    out[(size_t)g * F + f] = m;
}

// narrow fp32 GEMM NC=32, W staged in LDS
__global__ __launch_bounds__(256) void k_gemm_n32(const float* __restrict__ A,
                                                  const float* __restrict__ W,
                                                  const float* __restrict__ bias,
                                                  float* __restrict__ C, int M, int K) {
    __shared__ float Ws[128 * 32];
    int tid = threadIdx.x;
    for (int i = tid; i < K * 32; i += 256) Ws[i] = W[i];
    __syncthreads();
    int row = blockIdx.x * 8 + (tid >> 5);
    int col = tid & 31;
    if (row >= M) return;
    float acc = bias[col];
    const float* a = &A[(size_t)row * K];
    for (int k = 0; k < K; ++k) acc = fmaf(a[k], Ws[k * 32 + col], acc);
    C[(size_t)row * 32 + col] = acc;
}

// per-graph: z = Z[r,:32] @ W5 + b5, max over graph rows
__global__ __launch_bounds__(320) void k_z5_segmax(const float* __restrict__ Z,
        const float* __restrict__ W, const float* __restrict__ bias,
        const int* __restrict__ bounds, float* __restrict__ out) {
    __shared__ float Ws[320];
    __shared__ float red[320];
    int t = threadIdx.x;
    Ws[t] = W[t];
    __syncthreads();
    int g = blockIdx.x;
    int col = t % 10, rs = t / 10;
    float bcol = bias[col];
    int s = bounds[g], e = bounds[g + 1];
    float m = -INFINITY;
    for (int r = s + rs; r < e; r += 32) {
        float acc = bcol;
        const float* a = &Z[(size_t)r * 32];
#pragma unroll
        for (int k = 0; k < 32; ++k) acc = fmaf(a[k], Ws[k * 10 + col], acc);
        m = fmaxf(m, acc);
    }
    red[t] = m;
    __syncthreads();
    for (int step = 16; step >= 1; step >>= 1) {
        if (rs < step) red[rs * 10 + col] = fmaxf(red[rs * 10 + col], red[(rs + step) * 10 + col]);
        __syncthreads();
    }
    if (rs == 0) out[(size_t)g * 10 + col] = red[col];
}

extern "C" void kernel_launch(void* const* d_in, const int* in_sizes, int n_in,
                              void* d_out, int out_size, void* d_ws, size_t ws_size,
                              hipStream_t stream) {
    const float* x  = (const float*)d_in[0];
    const int* ei   = (const int*)d_in[1];
    const int* batch= (const int*)d_in[2];
    const float* W1 = (const float*)d_in[3];
    const float* b1 = (const float*)d_in[4];
    const float* W2 = (const float*)d_in[5];
    const float* b2 = (const float*)d_in[6];
    const float* W3 = (const float*)d_in[7];
    const float* b3 = (const float*)d_in[8];
    const float* W4 = (const float*)d_in[9];
    const float* b4 = (const float*)d_in[10];
    const float* W5 = (const float*)d_in[11];
    const float* b5 = (const float*)d_in[12];

    const int N  = in_sizes[2];           // 50000
    const int F  = in_sizes[0] / N;       // 128
    const int E  = in_sizes[1] / 2;       // 400000
    const int C1 = in_sizes[4];           // 512
    const int C2 = in_sizes[6];           // 256
    const int C3 = in_sizes[8];           // 128
    const int C5 = in_sizes[12];          // 10
    const int G  = out_size / (C2 + C5);  // 512
    const int NB = DIV_UP(N, 1024);

    const int* srcp = ei;
    const int* dstp = ei + E;

    // ---- workspace layout (256B-aligned carve-outs) ----
    uintptr_t p = (uintptr_t)d_ws;
    auto carve = [&](size_t bytes) {
        uintptr_t r = p;
        p += (bytes + 255) & ~(size_t)255;
        return (void*)r;
    };
    int* hist    = (int*)carve(sizeof(int) * N);
    int* row_off = (int*)carve(sizeof(int) * (N + 1));
    int* cursor  = (int*)carve(sizeof(int) * N);
    int* bounds  = (int*)carve(sizeof(int) * (G + 1));
    int* bsum    = (int*)carve(sizeof(int) * NB);
    int* boff    = (int*)carve(sizeof(int) * NB);
    int* csr_src = (int*)carve(sizeof(int) * E);
    float* csr_w = (float*)carve(sizeof(float) * E);
    float* dinv  = (float*)carve(sizeof(float) * N);
    unsigned short* w1t = (unsigned short*)carve(sizeof(short) * F * C1);
    unsigned short* w2t = (unsigned short*)carve(sizeof(short) * C1 * C2);
    unsigned short* w3t = (unsigned short*)carve(sizeof(short) * C2 * C3);
    unsigned short* xb    = (unsigned short*)carve(sizeof(short) * (size_t)N * F);
    unsigned short* aggxb = (unsigned short*)carve(sizeof(short) * (size_t)N * F);
    unsigned short* h1b   = (unsigned short*)carve(sizeof(short) * (size_t)N * C1);
    unsigned short* t2b   = (unsigned short*)carve(sizeof(short) * (size_t)N * C2); // reused as z4
    unsigned short* h2b   = (unsigned short*)carve(sizeof(short) * (size_t)N * C2);
    float* z3 = (float*)carve(sizeof(float) * (size_t)N * C3);
    float* z4 = (float*)t2b;

    float* out     = (float*)d_out;
    float* out_emb = out + (size_t)G * C5;

    // ---- CSR build + dinv + graph bounds ----
    k_zero_i<<<DIV_UP(N, 256), 256, 0, stream>>>(hist, N);
    k_zero_i<<<DIV_UP(N, 256), 256, 0, stream>>>(cursor, N);
    k_hist<<<DIV_UP(E, 256), 256, 0, stream>>>(dstp, hist, E);
    k_scan_bsum<<<NB, 256, 0, stream>>>(hist, bsum, N);
    k_scan_boff<<<1, 1024, 0, stream>>>(bsum, boff, row_off, NB, N);
    k_scan_apply<<<NB, 256, 0, stream>>>(hist, boff, row_off, N);
    k_dinv<<<DIV_UP(N, 256), 256, 0, stream>>>(hist, dinv, N);
    k_bin<<<DIV_UP(E, 256), 256, 0, stream>>>(srcp, dstp, row_off, cursor, dinv,
                                              csr_src, csr_w, E);
    k_bounds<<<DIV_UP(G + 1, 256), 256, 0, stream>>>(batch, bounds, N, G);

    // ---- bf16 conversions ----
    k_f2b4<<<DIV_UP(N * F / 4, 256), 256, 0, stream>>>(x, xb, N * F / 4);
    k_wt<<<DIV_UP(F * C1, 256), 256, 0, stream>>>(W1, w1t, F, C1);
    k_wt<<<DIV_UP(C1 * C2, 256), 256, 0, stream>>>(W2, w2t, C1, C2);
    k_wt<<<DIV_UP(C2 * C3, 256), 256, 0, stream>>>(W3, w3t, C2, C3);

    // ---- layer 1: gather (bf16) -> MFMA GEMM + bias + leakyrelu -> h1 bf16 ----
    k_gather_b<128, 0, 1><<<DIV_UP(N, 16), 256, 0, stream>>>(
        xb, row_off, csr_src, csr_w, dinv, nullptr, nullptr, aggxb, N);
    dim3 g1(C1 / 128, DIV_UP(N, 128));
    k_gemm_mfma<1, 1><<<g1, 256, 0, stream>>>(aggxb, w1t, b1, h1b, N, F, C1);

    // ---- layer 2: MFMA GEMM -> t2 bf16 -> gather (+b2) -> h2 bf16 only ----
    dim3 g2(C2 / 128, DIV_UP(N, 128));
    k_gemm_mfma<1, 0><<<g2, 256, 0, stream>>>(h1b, w2t, nullptr, t2b, N, C1, C2);
    k_gather_b<256, 0, 1><<<DIV_UP(N, 8), 256, 0, stream>>>(
        t2b, row_off, csr_src, csr_w, dinv, b2, nullptr, h2b, N);

    // ---- embs = segment_max(h2 bf16) ----
    k_segmax_sorted_b<256><<<G, 256, 0, stream>>>(h2b, bounds, out_emb);

    // ---- MLP head: MFMA L3 (fp32 out) -> fp32 n32 -> fused z5+segmax ----
    dim3 g3(C3 / 128, DIV_UP(N, 128));
    k_gemm_mfma<0, 0><<<g3, 256, 0, stream>>>(h2b, w3t, b3, z3, N, C2, C3);
    k_gemm_n32<<<DIV_UP(N, 8), 256, 0, stream>>>(z3, W4, b4, z4, N, C3);
    k_z5_segmax<<<G, 320, 0, stream>>>(z4, W5, b5, bounds, out);
}

// Round 7
// 357.442 us; speedup vs baseline: 7.3536x; 1.0235x over previous
//
#include <hip/hip_runtime.h>
#include <math.h>

#define DIV_UP(a,b) (((a)+(b)-1)/(b))

typedef __attribute__((ext_vector_type(8))) short bf16x8;
typedef __attribute__((ext_vector_type(4))) float f32x4;

// fp32 -> bf16 round-to-nearest-even
__device__ inline unsigned short f2b(float x) {
    unsigned int u = __float_as_uint(x);
    u += 0x7fffu + ((u >> 16) & 1u);
    return (unsigned short)(u >> 16);
}

// 8 packed bf16 (uint4) -> 8 floats
__device__ inline void cvt8(uint4 v, float* a) {
    a[0] = __uint_as_float(v.x << 16); a[1] = __uint_as_float(v.x & 0xffff0000u);
    a[2] = __uint_as_float(v.y << 16); a[3] = __uint_as_float(v.y & 0xffff0000u);
    a[4] = __uint_as_float(v.z << 16); a[5] = __uint_as_float(v.z & 0xffff0000u);
    a[6] = __uint_as_float(v.w << 16); a[7] = __uint_as_float(v.w & 0xffff0000u);
}

// async global->LDS 16B: per-lane global addr, LDS dest = wave-uniform base + lane*16
__device__ inline void gl16(void* lds, const void* g) {
    __builtin_amdgcn_global_load_lds(
        (const __attribute__((address_space(1))) void*)g,
        (__attribute__((address_space(3))) void*)lds, 16, 0, 0);
}

__global__ void k_zero_i(int* p, int n) {
    int i = blockIdx.x * blockDim.x + threadIdx.x;
    if (i < n) p[i] = 0;
}

__global__ void k_hist(const int* __restrict__ dst, int* __restrict__ hist, int E) {
    int i = blockIdx.x * blockDim.x + threadIdx.x;
    if (i < E) atomicAdd(&hist[dst[i]], 1);
}

// ---- hierarchical scan: 1024 elements per block ----
__global__ __launch_bounds__(256) void k_scan_bsum(const int* __restrict__ hist,
                                                   int* __restrict__ bsum, int N) {
    __shared__ int red[256];
    int t = threadIdx.x;
    int base = blockIdx.x * 1024 + t * 4;
    int s = 0;
    if (base + 3 < N) {
        int4 v = *(const int4*)&hist[base];
        s = v.x + v.y + v.z + v.w;
    } else {
        for (int j = 0; j < 4; ++j) if (base + j < N) s += hist[base + j];
    }
    red[t] = s;
    __syncthreads();
    for (int off = 128; off >= 1; off >>= 1) {
        if (t < off) red[t] += red[t + off];
        __syncthreads();
    }
    if (t == 0) bsum[blockIdx.x] = red[0];
}

__global__ __launch_bounds__(1024) void k_scan_boff(const int* __restrict__ bsum,
        int* __restrict__ boff, int* __restrict__ row_off, int NB, int N) {
    __shared__ int s[1024];
    int t = threadIdx.x;
    int v = (t < NB) ? bsum[t] : 0;
    s[t] = v;
    __syncthreads();
    for (int off = 1; off < 1024; off <<= 1) {
        int u = (t >= off) ? s[t - off] : 0;
        __syncthreads();
        s[t] += u;
        __syncthreads();
    }
    if (t < NB) boff[t] = s[t] - v;
    if (t == NB - 1) row_off[N] = s[t];
}

// scan apply + dinv fused (dinv[i] = rsqrt(1 + deg) — self-loop contributes 1)
__global__ __launch_bounds__(256) void k_scan_apply(const int* __restrict__ hist,
        const int* __restrict__ boff, int* __restrict__ row_off,
        float* __restrict__ dinv, int N) {
    __shared__ int s[256];
    int t = threadIdx.x;
    int base = blockIdx.x * 1024 + t * 4;
    int v[4];
    int loc = 0;
#pragma unroll
    for (int j = 0; j < 4; ++j) { v[j] = (base + j < N) ? hist[base + j] : 0; loc += v[j]; }
    s[t] = loc;
    __syncthreads();
    for (int off = 1; off < 256; off <<= 1) {
        int u = (t >= off) ? s[t - off] : 0;
        __syncthreads();
        s[t] += u;
        __syncthreads();
    }
    int run = boff[blockIdx.x] + s[t] - loc;
#pragma unroll
    for (int j = 0; j < 4; ++j) {
        if (base + j < N) {
            row_off[base + j] = run;
            dinv[base + j] = rsqrtf((float)(v[j] + 1));
        }
        run += v[j];
    }
}

__global__ void k_bin(const int* __restrict__ src, const int* __restrict__ dst,
                      const int* __restrict__ row_off, int* __restrict__ cursor,
                      const float* __restrict__ dinv,
                      int* __restrict__ csr_src, float* __restrict__ csr_w, int E) {
    int i = blockIdx.x * blockDim.x + threadIdx.x;
    if (i >= E) return;
    int d = dst[i], s = src[i];
    int pos = row_off[d] + atomicAdd(&cursor[d], 1);
    csr_src[pos] = s;
    csr_w[pos] = dinv[s] * dinv[d];
}

__global__ void k_bounds(const int* __restrict__ batch, int* __restrict__ bounds,
                         int N, int G) {
    int g = blockIdx.x * blockDim.x + threadIdx.x;
    if (g > G) return;
    int lo = 0, hi = N;
    while (lo < hi) { int mid = (lo + hi) >> 1; if (batch[mid] < g) lo = mid + 1; else hi = mid; }
    bounds[g] = lo;
}

// fp32[4] -> bf16[4] elementwise convert
__global__ void k_f2b4(const float* __restrict__ in, unsigned short* __restrict__ out, int n4) {
    int i = blockIdx.x * blockDim.x + threadIdx.x;
    if (i >= n4) return;
    float4 v = ((const float4*)in)[i];
    ushort4 o;
    o.x = f2b(v.x); o.y = f2b(v.y); o.z = f2b(v.z); o.w = f2b(v.w);
    ((ushort4*)out)[i] = o;
}

// weight transpose+convert: out_bf16[n*K + k] = in[k*NC + n]
__global__ void k_wt(const float* __restrict__ in, unsigned short* __restrict__ out,
                     int K, int NC) {
    int i = blockIdx.x * blockDim.x + threadIdx.x;
    if (i >= K * NC) return;
    int k = i / NC, n = i % NC;
    out[(size_t)n * K + k] = f2b(in[i]);
}

// head-weight precompute (fp32, one block):
// WcT[c,k] = (W3 @ W4 @ W5)[k,c],  bc = (b3@W4 + b4)@W5 + b5
__global__ __launch_bounds__(256) void k_wc(const float* __restrict__ W3,
        const float* __restrict__ W4, const float* __restrict__ W5,
        const float* __restrict__ b3, const float* __restrict__ b4,
        const float* __restrict__ b5, float* __restrict__ WcT, float* __restrict__ bc) {
    __shared__ float T[128 * 10];   // W4@W5
    __shared__ float v[32];
    int t = threadIdx.x;
    for (int i = t; i < 1280; i += 256) {
        int j = i / 10, c = i % 10;
        float s = 0.f;
        for (int k = 0; k < 32; ++k) s = fmaf(W4[j * 32 + k], W5[k * 10 + c], s);
        T[i] = s;
    }
    if (t < 32) {
        float s = b4[t];
        for (int j = 0; j < 128; ++j) s = fmaf(b3[j], W4[j * 32 + t], s);
        v[t] = s;
    }
    __syncthreads();
    for (int i = t; i < 2560; i += 256) {
        int c = i / 256, k = i % 256;
        float s = 0.f;
        for (int j = 0; j < 128; ++j) s = fmaf(W3[k * 128 + j], T[j * 10 + c], s);
        WcT[c * 256 + k] = s;
    }
    if (t < 10) {
        float s = b5[t];
        for (int k = 0; k < 32; ++k) s = fmaf(v[k], W5[k * 10 + t], s);
        bc[t] = s;
    }
}

// gather-aggregate over dst-CSR, bf16 in/out, ILP-4 edge loop.
// out[i,:] = dinv[i]^2*H[i,:] (+bias) + sum_j w_j*H[src_j,:]
template <int F>
__global__ __launch_bounds__(256) void k_gather_b(const unsigned short* __restrict__ H,
        const int* __restrict__ row_off, const int* __restrict__ csr_src,
        const float* __restrict__ csr_w, const float* __restrict__ dinv,
        const float* __restrict__ bias, unsigned short* __restrict__ outb, int N) {
    const int LPN = F / 8;
    const int NPB = 256 / LPN;
    int node = blockIdx.x * NPB + threadIdx.x / LPN;
    if (node >= N) return;
    int f = (threadIdx.x % LPN) * 8;
    const unsigned short* Hf = H + f;
    float sc = dinv[node]; sc *= sc;
    float a[8];
    cvt8(*(const uint4*)&Hf[(size_t)node * F], a);
#pragma unroll
    for (int j = 0; j < 8; ++j) a[j] *= sc;
    if (bias) {
#pragma unroll
        for (int j = 0; j < 8; ++j) a[j] += bias[f + j];
    }
    int e0 = row_off[node], e1 = row_off[node + 1];
    int e = e0;
    // 4 independent row fetches in flight per iteration (latency hiding)
    for (; e + 4 <= e1; e += 4) {
        int s0 = csr_src[e + 0], s1 = csr_src[e + 1];
        int s2 = csr_src[e + 2], s3 = csr_src[e + 3];
        uint4 v0 = *(const uint4*)&Hf[(size_t)s0 * F];
        uint4 v1 = *(const uint4*)&Hf[(size_t)s1 * F];
        uint4 v2 = *(const uint4*)&Hf[(size_t)s2 * F];
        uint4 v3 = *(const uint4*)&Hf[(size_t)s3 * F];
        float w0 = csr_w[e + 0], w1 = csr_w[e + 1];
        float w2 = csr_w[e + 2], w3 = csr_w[e + 3];
        float b0[8], b1[8], b2[8], b3[8];
        cvt8(v0, b0); cvt8(v1, b1); cvt8(v2, b2); cvt8(v3, b3);
#pragma unroll
        for (int j = 0; j < 8; ++j) {
            a[j] = fmaf(w0, b0[j], a[j]);
            a[j] = fmaf(w1, b1[j], a[j]);
            a[j] = fmaf(w2, b2[j], a[j]);
            a[j] = fmaf(w3, b3[j], a[j]);
        }
    }
    for (; e < e1; ++e) {
        int s = csr_src[e];
        float w = csr_w[e];
        float b[8];
        cvt8(*(const uint4*)&Hf[(size_t)s * F], b);
#pragma unroll
        for (int j = 0; j < 8; ++j) a[j] = fmaf(w, b[j], a[j]);
    }
    uint4 o;
    o.x = (unsigned)f2b(a[0]) | ((unsigned)f2b(a[1]) << 16);
    o.y = (unsigned)f2b(a[2]) | ((unsigned)f2b(a[3]) << 16);
    o.z = (unsigned)f2b(a[4]) | ((unsigned)f2b(a[5]) << 16);
    o.w = (unsigned)f2b(a[6]) | ((unsigned)f2b(a[7]) << 16);
    *(uint4*)&outb[(size_t)node * F + f] = o;
}

// bf16 MFMA GEMM: C[M,NC] = act(A[M,K] @ B[K,NC] + bias)  (see round-6 notes)
// 128x128 tile, BK=64, global_load_lds w16, XOR-swizzled LDS, operand-swap mfma.
template <int OUT_BF16, int ACT>
__global__ __launch_bounds__(256) void k_gemm_mfma(const unsigned short* __restrict__ A,
        const unsigned short* __restrict__ Bt, const float* __restrict__ bias,
        void* __restrict__ Cout, int M, int K, int NC) {
    __shared__ __align__(16) unsigned short As[128][64];
    __shared__ __align__(16) unsigned short Bs[128][64];
    int tid = threadIdx.x;
    int wave = tid >> 6, lane = tid & 63;
    int row0 = blockIdx.y * 128, col0 = blockIdx.x * 128;
    int wr = (wave >> 1) * 64, wc = (wave & 1) * 64;
    f32x4 acc[4][4] = {};
    int lr = lane & 15;
    int lg = lane >> 4;
    int sw = ((lane & 7) ^ (lane >> 3)) << 3;
    int ch0 = (lg ^ (lr & 7)) << 3;
    int ch1 = ch0 ^ (4 << 3);

    for (int k0 = 0; k0 < K; k0 += 64) {
#pragma unroll
        for (int c = 0; c < 4; ++c) {
            int rl = wave * 32 + c * 8 + (lane >> 3);
            int gr = min(row0 + rl, M - 1);
            gl16(&As[wave * 32 + c * 8][0], &A[(size_t)gr * K + k0 + sw]);
            gl16(&Bs[wave * 32 + c * 8][0], &Bt[(size_t)(col0 + rl) * K + k0 + sw]);
        }
        __syncthreads();
        bf16x8 af[2][4], bv[2][4];
#pragma unroll
        for (int i = 0; i < 4; ++i) {
            int ra = wr + i * 16 + lr;
            int rb = wc + i * 16 + lr;
            af[0][i] = *(const bf16x8*)&As[ra][ch0];
            af[1][i] = *(const bf16x8*)&As[ra][ch1];
            bv[0][i] = *(const bf16x8*)&Bs[rb][ch0];
            bv[1][i] = *(const bf16x8*)&Bs[rb][ch1];
        }
#pragma unroll
        for (int s = 0; s < 2; ++s)
#pragma unroll
            for (int i = 0; i < 4; ++i)
#pragma unroll
                for (int j = 0; j < 4; ++j)
                    acc[i][j] = __builtin_amdgcn_mfma_f32_16x16x32_bf16(bv[s][j], af[s][i], acc[i][j], 0, 0, 0);
        __syncthreads();
    }

    int q4 = lg * 4;
    float4 bb[4];
#pragma unroll
    for (int j = 0; j < 4; ++j)
        bb[j] = bias ? *(const float4*)&bias[col0 + wc + j * 16 + q4]
                     : make_float4(0.f, 0.f, 0.f, 0.f);
#pragma unroll
    for (int i = 0; i < 4; ++i) {
        int row = row0 + wr + i * 16 + lr;
        if (row >= M) continue;
#pragma unroll
        for (int j = 0; j < 4; ++j) {
            int c0 = col0 + wc + j * 16 + q4;
            float4 v;
            v.x = acc[i][j][0] + bb[j].x;
            v.y = acc[i][j][1] + bb[j].y;
            v.z = acc[i][j][2] + bb[j].z;
            v.w = acc[i][j][3] + bb[j].w;
            if (ACT) {
                v.x = (v.x >= 0.f) ? v.x : 0.01f * v.x;
                v.y = (v.y >= 0.f) ? v.y : 0.01f * v.y;
                v.z = (v.z >= 0.f) ? v.z : 0.01f * v.z;
                v.w = (v.w >= 0.f) ? v.w : 0.01f * v.w;
            }
            if (OUT_BF16) {
                uint2 o;
                o.x = (unsigned)f2b(v.x) | ((unsigned)f2b(v.y) << 16);
                o.y = (unsigned)f2b(v.z) | ((unsigned)f2b(v.w) << 16);
                *(uint2*)&((unsigned short*)Cout)[(size_t)row * NC + c0] = o;
            } else {
                *(float4*)&((float*)Cout)[(size_t)row * NC + c0] = v;
            }
        }
    }
}

// segment_max over sorted ranges, bf16 input: block g, thread f
template <int F>
__global__ void k_segmax_sorted_b(const unsigned short* __restrict__ H,
                                  const int* __restrict__ bounds, float* __restrict__ out) {
    int g = blockIdx.x;
    int f = threadIdx.x;
    int s = bounds[g], e = bounds[g + 1];
    float m = -INFINITY;
    for (int r = s; r < e; ++r)
        m = fmaxf(m, __uint_as_float(((unsigned)H[(size_t)r * F + f]) << 16));
    out[(size_t)g * F + f] = m;
}

// fused head: out[g,c] = max over rows r in graph g of (h2[r,:] @ WcT[c,:] + bc[c])
__global__ __launch_bounds__(320) void k_head_segmax(const unsigned short* __restrict__ H,
        const float* __restrict__ WcT, const float* __restrict__ bc,
        const int* __restrict__ bounds, float* __restrict__ out) {
    __shared__ __align__(16) float Ws[10][260];  // +4 pad: 2-way max bank alias on b128 reads
    __shared__ float bs[10];
    __shared__ float red[320];
    int t = threadIdx.x;
    for (int i = t; i < 2560; i += 320) Ws[i / 256][i % 256] = WcT[i];
    if (t < 10) bs[t] = bc[t];
    __syncthreads();
    int g = blockIdx.x;
    int col = t % 10, rs = t / 10;
    int s = bounds[g], e = bounds[g + 1];
    float m = -INFINITY;
    for (int r = s + rs; r < e; r += 32) {
        const unsigned short* hr = &H[(size_t)r * 256];
        float acc = bs[col];
#pragma unroll 4
        for (int k = 0; k < 256; k += 8) {
            float h[8];
            cvt8(*(const uint4*)&hr[k], h);   // broadcast across the 10 cols
            float4 wa = *(const float4*)&Ws[col][k];
            float4 wb = *(const float4*)&Ws[col][k + 4];
            acc = fmaf(h[0], wa.x, acc);
            acc = fmaf(h[1], wa.y, acc);
            acc = fmaf(h[2], wa.z, acc);
            acc = fmaf(h[3], wa.w, acc);
            acc = fmaf(h[4], wb.x, acc);
            acc = fmaf(h[5], wb.y, acc);
            acc = fmaf(h[6], wb.z, acc);
            acc = fmaf(h[7], wb.w, acc);
        }
        m = fmaxf(m, acc);
    }
    red[t] = m;
    __syncthreads();
    for (int step = 16; step >= 1; step >>= 1) {
        if (rs < step) red[rs * 10 + col] = fmaxf(red[rs * 10 + col], red[(rs + step) * 10 + col]);
        __syncthreads();
    }
    if (rs == 0) out[(size_t)g * 10 + col] = red[col];
}

extern "C" void kernel_launch(void* const* d_in, const int* in_sizes, int n_in,
                              void* d_out, int out_size, void* d_ws, size_t ws_size,
                              hipStream_t stream) {
    const float* x  = (const float*)d_in[0];
    const int* ei   = (const int*)d_in[1];
    const int* batch= (const int*)d_in[2];
    const float* W1 = (const float*)d_in[3];
    const float* b1 = (const float*)d_in[4];
    const float* W2 = (const float*)d_in[5];
    const float* b2 = (const float*)d_in[6];
    const float* W3 = (const float*)d_in[7];
    const float* b3 = (const float*)d_in[8];
    const float* W4 = (const float*)d_in[9];
    const float* b4 = (const float*)d_in[10];
    const float* W5 = (const float*)d_in[11];
    const float* b5 = (const float*)d_in[12];

    const int N  = in_sizes[2];           // 50000
    const int F  = in_sizes[0] / N;       // 128
    const int E  = in_sizes[1] / 2;       // 400000
    const int C1 = in_sizes[4];           // 512
    const int C2 = in_sizes[6];           // 256
    const int C5 = in_sizes[12];          // 10
    const int G  = out_size / (C2 + C5);  // 512
    const int NB = DIV_UP(N, 1024);

    const int* srcp = ei;
    const int* dstp = ei + E;

    // ---- workspace layout (256B-aligned carve-outs) ----
    uintptr_t p = (uintptr_t)d_ws;
    auto carve = [&](size_t bytes) {
        uintptr_t r = p;
        p += (bytes + 255) & ~(size_t)255;
        return (void*)r;
    };
    int* hist    = (int*)carve(sizeof(int) * N);
    int* cursor  = (int*)carve(sizeof(int) * N);      // MUST follow hist (joint zero-fill)
    int* row_off = (int*)carve(sizeof(int) * (N + 1));
    int* bounds  = (int*)carve(sizeof(int) * (G + 1));
    int* bsum    = (int*)carve(sizeof(int) * NB);
    int* boff    = (int*)carve(sizeof(int) * NB);
    int* csr_src = (int*)carve(sizeof(int) * E);
    float* csr_w = (float*)carve(sizeof(float) * E);
    float* dinv  = (float*)carve(sizeof(float) * N);
    float* wct   = (float*)carve(sizeof(float) * C2 * C5);
    float* bcv   = (float*)carve(sizeof(float) * C5);
    unsigned short* w1t = (unsigned short*)carve(sizeof(short) * F * C1);
    unsigned short* w2t = (unsigned short*)carve(sizeof(short) * C1 * C2);
    unsigned short* xb    = (unsigned short*)carve(sizeof(short) * (size_t)N * F);
    unsigned short* aggxb = (unsigned short*)carve(sizeof(short) * (size_t)N * F);
    unsigned short* h1b   = (unsigned short*)carve(sizeof(short) * (size_t)N * C1);
    unsigned short* t2b   = (unsigned short*)carve(sizeof(short) * (size_t)N * C2);
    unsigned short* h2b   = (unsigned short*)carve(sizeof(short) * (size_t)N * C2);

    float* out     = (float*)d_out;
    float* out_emb = out + (size_t)G * C5;

    // ---- CSR build + dinv + graph bounds + head-weight precompute ----
    int zspan = (int)(((sizeof(int) * N + 255) & ~(size_t)255) / 4) + N;  // hist..cursor
    k_zero_i<<<DIV_UP(zspan, 256), 256, 0, stream>>>(hist, zspan);
    k_hist<<<DIV_UP(E, 256), 256, 0, stream>>>(dstp, hist, E);
    k_scan_bsum<<<NB, 256, 0, stream>>>(hist, bsum, N);
    k_scan_boff<<<1, 1024, 0, stream>>>(bsum, boff, row_off, NB, N);
    k_scan_apply<<<NB, 256, 0, stream>>>(hist, boff, row_off, dinv, N);
    k_bin<<<DIV_UP(E, 256), 256, 0, stream>>>(srcp, dstp, row_off, cursor, dinv,
                                              csr_src, csr_w, E);
    k_bounds<<<DIV_UP(G + 1, 256), 256, 0, stream>>>(batch, bounds, N, G);
    k_wc<<<1, 256, 0, stream>>>(W3, W4, W5, b3, b4, b5, wct, bcv);

    // ---- bf16 conversions ----
    k_f2b4<<<DIV_UP(N * F / 4, 256), 256, 0, stream>>>(x, xb, N * F / 4);
    k_wt<<<DIV_UP(F * C1, 256), 256, 0, stream>>>(W1, w1t, F, C1);
    k_wt<<<DIV_UP(C1 * C2, 256), 256, 0, stream>>>(W2, w2t, C1, C2);

    // ---- layer 1: gather (bf16) -> MFMA GEMM + bias + leakyrelu -> h1 bf16 ----
    k_gather_b<128><<<DIV_UP(N, 16), 256, 0, stream>>>(
        xb, row_off, csr_src, csr_w, dinv, nullptr, aggxb, N);
    dim3 g1(C1 / 128, DIV_UP(N, 128));
    k_gemm_mfma<1, 1><<<g1, 256, 0, stream>>>(aggxb, w1t, b1, h1b, N, F, C1);

    // ---- layer 2: MFMA GEMM -> t2 bf16 -> gather (+b2) -> h2 bf16 ----
    dim3 g2(C2 / 128, DIV_UP(N, 128));
    k_gemm_mfma<1, 0><<<g2, 256, 0, stream>>>(h1b, w2t, nullptr, t2b, N, C1, C2);
    k_gather_b<256><<<DIV_UP(N, 8), 256, 0, stream>>>(
        t2b, row_off, csr_src, csr_w, dinv, b2, h2b, N);

    // ---- embs = segment_max(h2 bf16) ----
    k_segmax_sorted_b<256><<<G, 256, 0, stream>>>(h2b, bounds, out_emb);

    // ---- fused MLP head + segment_max (W3·W4·W5 collapsed) ----
    k_head_segmax<<<G, 320, 0, stream>>>(h2b, wct, bcv, bounds, out);
}

// Round 8
// 310.429 us; speedup vs baseline: 8.4673x; 1.1514x over previous
//
#include <hip/hip_runtime.h>
#include <math.h>

#define DIV_UP(a,b) (((a)+(b)-1)/(b))

typedef __attribute__((ext_vector_type(8))) short bf16x8;
typedef __attribute__((ext_vector_type(4))) float f32x4;

// fp32 -> bf16 round-to-nearest-even
__device__ inline unsigned short f2b(float x) {
    unsigned int u = __float_as_uint(x);
    u += 0x7fffu + ((u >> 16) & 1u);
    return (unsigned short)(u >> 16);
}

// 8 packed bf16 (uint4) -> 8 floats
__device__ inline void cvt8(uint4 v, float* a) {
    a[0] = __uint_as_float(v.x << 16); a[1] = __uint_as_float(v.x & 0xffff0000u);
    a[2] = __uint_as_float(v.y << 16); a[3] = __uint_as_float(v.y & 0xffff0000u);
    a[4] = __uint_as_float(v.z << 16); a[5] = __uint_as_float(v.z & 0xffff0000u);
    a[6] = __uint_as_float(v.w << 16); a[7] = __uint_as_float(v.w & 0xffff0000u);
}

// async global->LDS 16B
__device__ inline void gl16(void* lds, const void* g) {
    __builtin_amdgcn_global_load_lds(
        (const __attribute__((address_space(1))) void*)g,
        (__attribute__((address_space(3))) void*)lds, 16, 0, 0);
}

__global__ void k_zero_i(int* p, int n) {
    int i = blockIdx.x * blockDim.x + threadIdx.x;
    if (i < n) p[i] = 0;
}

__global__ void k_hist(const int* __restrict__ dst, int* __restrict__ hist, int E) {
    int i = blockIdx.x * blockDim.x + threadIdx.x;
    if (i < E) atomicAdd(&hist[dst[i]], 1);
}

// ---- hierarchical scan ----
__global__ __launch_bounds__(256) void k_scan_bsum(const int* __restrict__ hist,
                                                   int* __restrict__ bsum, int N) {
    __shared__ int red[256];
    int t = threadIdx.x;
    int base = blockIdx.x * 1024 + t * 4;
    int s = 0;
    if (base + 3 < N) {
        int4 v = *(const int4*)&hist[base];
        s = v.x + v.y + v.z + v.w;
    } else {
        for (int j = 0; j < 4; ++j) if (base + j < N) s += hist[base + j];
    }
    red[t] = s;
    __syncthreads();
    for (int off = 128; off >= 1; off >>= 1) {
        if (t < off) red[t] += red[t + off];
        __syncthreads();
    }
    if (t == 0) bsum[blockIdx.x] = red[0];
}

__global__ __launch_bounds__(1024) void k_scan_boff(const int* __restrict__ bsum,
        int* __restrict__ boff, int* __restrict__ row_off, int NB, int N) {
    __shared__ int s[1024];
    int t = threadIdx.x;
    int v = (t < NB) ? bsum[t] : 0;
    s[t] = v;
    __syncthreads();
    for (int off = 1; off < 1024; off <<= 1) {
        int u = (t >= off) ? s[t - off] : 0;
        __syncthreads();
        s[t] += u;
        __syncthreads();
    }
    if (t < NB) boff[t] = s[t] - v;
    if (t == NB - 1) row_off[N] = s[t];
}

// scan apply + dinv fused
__global__ __launch_bounds__(256) void k_scan_apply(const int* __restrict__ hist,
        const int* __restrict__ boff, int* __restrict__ row_off,
        float* __restrict__ dinv, int N) {
    __shared__ int s[256];
    int t = threadIdx.x;
    int base = blockIdx.x * 1024 + t * 4;
    int v[4];
    int loc = 0;
#pragma unroll
    for (int j = 0; j < 4; ++j) { v[j] = (base + j < N) ? hist[base + j] : 0; loc += v[j]; }
    s[t] = loc;
    __syncthreads();
    for (int off = 1; off < 256; off <<= 1) {
        int u = (t >= off) ? s[t - off] : 0;
        __syncthreads();
        s[t] += u;
        __syncthreads();
    }
    int run = boff[blockIdx.x] + s[t] - loc;
#pragma unroll
    for (int j = 0; j < 4; ++j) {
        if (base + j < N) {
            row_off[base + j] = run;
            dinv[base + j] = rsqrtf((float)(v[j] + 1));
        }
        run += v[j];
    }
}

__global__ void k_bin(const int* __restrict__ src, const int* __restrict__ dst,
                      const int* __restrict__ row_off, int* __restrict__ cursor,
                      const float* __restrict__ dinv,
                      int* __restrict__ csr_src, float* __restrict__ csr_w, int E) {
    int i = blockIdx.x * blockDim.x + threadIdx.x;
    if (i >= E) return;
    int d = dst[i], s = src[i];
    int pos = row_off[d] + atomicAdd(&cursor[d], 1);
    csr_src[pos] = s;
    csr_w[pos] = dinv[s] * dinv[d];
}

__global__ void k_bounds(const int* __restrict__ batch, int* __restrict__ bounds,
                         int N, int G) {
    int g = blockIdx.x * blockDim.x + threadIdx.x;
    if (g > G) return;
    int lo = 0, hi = N;
    while (lo < hi) { int mid = (lo + hi) >> 1; if (batch[mid] < g) lo = mid + 1; else hi = mid; }
    bounds[g] = lo;
}

// fused prep: x->bf16 (n4 ushort4 groups), then W1^T, then W2^T (bf16)
__global__ void k_prep(const float* __restrict__ x, unsigned short* __restrict__ xb, int n4,
                       const float* __restrict__ W1, unsigned short* __restrict__ w1t,
                       int K1, int N1,
                       const float* __restrict__ W2, unsigned short* __restrict__ w2t,
                       int K2, int N2) {
    int i = blockIdx.x * blockDim.x + threadIdx.x;
    if (i < n4) {
        float4 v = ((const float4*)x)[i];
        ushort4 o;
        o.x = f2b(v.x); o.y = f2b(v.y); o.z = f2b(v.z); o.w = f2b(v.w);
        ((ushort4*)xb)[i] = o;
        return;
    }
    i -= n4;
    if (i < K1 * N1) {
        int k = i / N1, n = i % N1;
        w1t[(size_t)n * K1 + k] = f2b(W1[i]);
        return;
    }
    i -= K1 * N1;
    if (i < K2 * N2) {
        int k = i / N2, n = i % N2;
        w2t[(size_t)n * K2 + k] = f2b(W2[i]);
    }
}

// head-weight precompute, parallel: blocks 0..9 compute WcT row c; block 10 bias chain.
// WcT[c,k] = (W3 @ W4 @ W5)[k,c]; bc = (b3@W4 + b4)@W5 + b5
__global__ __launch_bounds__(256) void k_wc(const float* __restrict__ W3,
        const float* __restrict__ W4, const float* __restrict__ W5,
        const float* __restrict__ b3, const float* __restrict__ b4,
        const float* __restrict__ b5, float* __restrict__ WcT, float* __restrict__ bc) {
    int c = blockIdx.x;
    int t = threadIdx.x;
    if (c < 10) {
        __shared__ float Tc[128];          // column c of W4@W5
        if (t < 128) {
            float s = 0.f;
#pragma unroll 8
            for (int k = 0; k < 32; ++k) s = fmaf(W4[t * 32 + k], W5[k * 10 + c], s);
            Tc[t] = s;
        }
        __syncthreads();
        // thread t=k: contiguous row k of W3 (128 floats)
        float s = 0.f;
        const float* w3r = &W3[t * 128];
#pragma unroll 8
        for (int j = 0; j < 128; ++j) s = fmaf(w3r[j], Tc[j], s);
        WcT[c * 256 + t] = s;
    } else {
        __shared__ float v[32];
        if (t < 32) {
            float s = b4[t];
            for (int j = 0; j < 128; ++j) s = fmaf(b3[j], W4[j * 32 + t], s);
            v[t] = s;
        }
        __syncthreads();
        if (t < 10) {
            float s = b5[t];
            for (int k = 0; k < 32; ++k) s = fmaf(v[k], W5[k * 10 + t], s);
            bc[t] = s;
        }
    }
}

// gather-aggregate over dst-CSR, bf16 in/out, ILP-4 edge loop.
template <int F>
__global__ __launch_bounds__(256) void k_gather_b(const unsigned short* __restrict__ H,
        const int* __restrict__ row_off, const int* __restrict__ csr_src,
        const float* __restrict__ csr_w, const float* __restrict__ dinv,
        const float* __restrict__ bias, unsigned short* __restrict__ outb, int N) {
    const int LPN = F / 8;
    const int NPB = 256 / LPN;
    int node = blockIdx.x * NPB + threadIdx.x / LPN;
    if (node >= N) return;
    int f = (threadIdx.x % LPN) * 8;
    const unsigned short* Hf = H + f;
    float sc = dinv[node]; sc *= sc;
    float a[8];
    cvt8(*(const uint4*)&Hf[(size_t)node * F], a);
#pragma unroll
    for (int j = 0; j < 8; ++j) a[j] *= sc;
    if (bias) {
#pragma unroll
        for (int j = 0; j < 8; ++j) a[j] += bias[f + j];
    }
    int e0 = row_off[node], e1 = row_off[node + 1];
    int e = e0;
    for (; e + 4 <= e1; e += 4) {
        int s0 = csr_src[e + 0], s1 = csr_src[e + 1];
        int s2 = csr_src[e + 2], s3 = csr_src[e + 3];
        uint4 v0 = *(const uint4*)&Hf[(size_t)s0 * F];
        uint4 v1 = *(const uint4*)&Hf[(size_t)s1 * F];
        uint4 v2 = *(const uint4*)&Hf[(size_t)s2 * F];
        uint4 v3 = *(const uint4*)&Hf[(size_t)s3 * F];
        float w0 = csr_w[e + 0], w1 = csr_w[e + 1];
        float w2 = csr_w[e + 2], w3 = csr_w[e + 3];
        float b0[8], b1[8], b2[8], b3[8];
        cvt8(v0, b0); cvt8(v1, b1); cvt8(v2, b2); cvt8(v3, b3);
#pragma unroll
        for (int j = 0; j < 8; ++j) {
            a[j] = fmaf(w0, b0[j], a[j]);
            a[j] = fmaf(w1, b1[j], a[j]);
            a[j] = fmaf(w2, b2[j], a[j]);
            a[j] = fmaf(w3, b3[j], a[j]);
        }
    }
    for (; e < e1; ++e) {
        int s = csr_src[e];
        float w = csr_w[e];
        float b[8];
        cvt8(*(const uint4*)&Hf[(size_t)s * F], b);
#pragma unroll
        for (int j = 0; j < 8; ++j) a[j] = fmaf(w, b[j], a[j]);
    }
    uint4 o;
    o.x = (unsigned)f2b(a[0]) | ((unsigned)f2b(a[1]) << 16);
    o.y = (unsigned)f2b(a[2]) | ((unsigned)f2b(a[3]) << 16);
    o.z = (unsigned)f2b(a[4]) | ((unsigned)f2b(a[5]) << 16);
    o.w = (unsigned)f2b(a[6]) | ((unsigned)f2b(a[7]) << 16);
    *(uint4*)&outb[(size_t)node * F + f] = o;
}

// bf16 MFMA GEMM: 128x128 tile, BK=64, global_load_lds w16, XOR-swizzle, operand-swap.
template <int OUT_BF16, int ACT>
__global__ __launch_bounds__(256) void k_gemm_mfma(const unsigned short* __restrict__ A,
        const unsigned short* __restrict__ Bt, const float* __restrict__ bias,
        void* __restrict__ Cout, int M, int K, int NC) {
    __shared__ __align__(16) unsigned short As[128][64];
    __shared__ __align__(16) unsigned short Bs[128][64];
    int tid = threadIdx.x;
    int wave = tid >> 6, lane = tid & 63;
    int row0 = blockIdx.y * 128, col0 = blockIdx.x * 128;
    int wr = (wave >> 1) * 64, wc = (wave & 1) * 64;
    f32x4 acc[4][4] = {};
    int lr = lane & 15;
    int lg = lane >> 4;
    int sw = ((lane & 7) ^ (lane >> 3)) << 3;
    int ch0 = (lg ^ (lr & 7)) << 3;
    int ch1 = ch0 ^ (4 << 3);

    for (int k0 = 0; k0 < K; k0 += 64) {
#pragma unroll
        for (int c = 0; c < 4; ++c) {
            int rl = wave * 32 + c * 8 + (lane >> 3);
            int gr = min(row0 + rl, M - 1);
            gl16(&As[wave * 32 + c * 8][0], &A[(size_t)gr * K + k0 + sw]);
            gl16(&Bs[wave * 32 + c * 8][0], &Bt[(size_t)(col0 + rl) * K + k0 + sw]);
        }
        __syncthreads();
        bf16x8 af[2][4], bv[2][4];
#pragma unroll
        for (int i = 0; i < 4; ++i) {
            int ra = wr + i * 16 + lr;
            int rb = wc + i * 16 + lr;
            af[0][i] = *(const bf16x8*)&As[ra][ch0];
            af[1][i] = *(const bf16x8*)&As[ra][ch1];
            bv[0][i] = *(const bf16x8*)&Bs[rb][ch0];
            bv[1][i] = *(const bf16x8*)&Bs[rb][ch1];
        }
#pragma unroll
        for (int s = 0; s < 2; ++s)
#pragma unroll
            for (int i = 0; i < 4; ++i)
#pragma unroll
                for (int j = 0; j < 4; ++j)
                    acc[i][j] = __builtin_amdgcn_mfma_f32_16x16x32_bf16(bv[s][j], af[s][i], acc[i][j], 0, 0, 0);
        __syncthreads();
    }

    int q4 = lg * 4;
    float4 bb[4];
#pragma unroll
    for (int j = 0; j < 4; ++j)
        bb[j] = bias ? *(const float4*)&bias[col0 + wc + j * 16 + q4]
                     : make_float4(0.f, 0.f, 0.f, 0.f);
#pragma unroll
    for (int i = 0; i < 4; ++i) {
        int row = row0 + wr + i * 16 + lr;
        if (row >= M) continue;
#pragma unroll
        for (int j = 0; j < 4; ++j) {
            int c0 = col0 + wc + j * 16 + q4;
            float4 v;
            v.x = acc[i][j][0] + bb[j].x;
            v.y = acc[i][j][1] + bb[j].y;
            v.z = acc[i][j][2] + bb[j].z;
            v.w = acc[i][j][3] + bb[j].w;
            if (ACT) {
                v.x = (v.x >= 0.f) ? v.x : 0.01f * v.x;
                v.y = (v.y >= 0.f) ? v.y : 0.01f * v.y;
                v.z = (v.z >= 0.f) ? v.z : 0.01f * v.z;
                v.w = (v.w >= 0.f) ? v.w : 0.01f * v.w;
            }
            if (OUT_BF16) {
                uint2 o;
                o.x = (unsigned)f2b(v.x) | ((unsigned)f2b(v.y) << 16);
                o.y = (unsigned)f2b(v.z) | ((unsigned)f2b(v.w) << 16);
                *(uint2*)&((unsigned short*)Cout)[(size_t)row * NC + c0] = o;
            } else {
                *(float4*)&((float*)Cout)[(size_t)row * NC + c0] = v;
            }
        }
    }
}

// fused per-graph output: phase A = head (h2 @ Wc + bc, max over rows -> out[g,:10]);
// phase B = feature-wise segment_max of h2 -> out_emb[g,:256].
__global__ __launch_bounds__(320) void k_head_segmax(const unsigned short* __restrict__ H,
        const float* __restrict__ WcT, const float* __restrict__ bc,
        const int* __restrict__ bounds, float* __restrict__ out,
        float* __restrict__ out_emb) {
    __shared__ __align__(16) float Ws[10][260];
    __shared__ float bs[10];
    __shared__ float red[320];
    int t = threadIdx.x;
    for (int i = t; i < 2560; i += 320) Ws[i / 256][i % 256] = WcT[i];
    if (t < 10) bs[t] = bc[t];
    __syncthreads();
    int g = blockIdx.x;
    int s = bounds[g], e = bounds[g + 1];
    // ---- phase A: head ----
    int col = t % 10, rs = t / 10;
    float m = -INFINITY;
    for (int r = s + rs; r < e; r += 32) {
        const unsigned short* hr = &H[(size_t)r * 256];
        float acc = bs[col];
#pragma unroll 4
        for (int k = 0; k < 256; k += 8) {
            float h[8];
            cvt8(*(const uint4*)&hr[k], h);
            float4 wa = *(const float4*)&Ws[col][k];
            float4 wb = *(const float4*)&Ws[col][k + 4];
            acc = fmaf(h[0], wa.x, acc);
            acc = fmaf(h[1], wa.y, acc);
            acc = fmaf(h[2], wa.z, acc);
            acc = fmaf(h[3], wa.w, acc);
            acc = fmaf(h[4], wb.x, acc);
            acc = fmaf(h[5], wb.y, acc);
            acc = fmaf(h[6], wb.z, acc);
            acc = fmaf(h[7], wb.w, acc);
        }
        m = fmaxf(m, acc);
    }
    red[t] = m;
    __syncthreads();
    for (int step = 16; step >= 1; step >>= 1) {
        if (rs < step) red[rs * 10 + col] = fmaxf(red[rs * 10 + col], red[(rs + step) * 10 + col]);
        __syncthreads();
    }
    if (rs == 0) out[(size_t)g * 10 + col] = red[col];
    // ---- phase B: embs segment_max (first 256 threads, feature t) ----
    if (t < 256) {
        float mm = -INFINITY;
        for (int r = s; r < e; ++r)
            mm = fmaxf(mm, __uint_as_float(((unsigned)H[(size_t)r * 256 + t]) << 16));
        out_emb[(size_t)g * 256 + t] = mm;
    }
}

extern "C" void kernel_launch(void* const* d_in, const int* in_sizes, int n_in,
                              void* d_out, int out_size, void* d_ws, size_t ws_size,
                              hipStream_t stream) {
    const float* x  = (const float*)d_in[0];
    const int* ei   = (const int*)d_in[1];
    const int* batch= (const int*)d_in[2];
    const float* W1 = (const float*)d_in[3];
    const float* b1 = (const float*)d_in[4];
    const float* W2 = (const float*)d_in[5];
    const float* b2 = (const float*)d_in[6];
    const float* W3 = (const float*)d_in[7];
    const float* b3 = (const float*)d_in[8];
    const float* W4 = (const float*)d_in[9];
    const float* b4 = (const float*)d_in[10];
    const float* W5 = (const float*)d_in[11];
    const float* b5 = (const float*)d_in[12];

    const int N  = in_sizes[2];           // 50000
    const int F  = in_sizes[0] / N;       // 128
    const int E  = in_sizes[1] / 2;       // 400000
    const int C1 = in_sizes[4];           // 512
    const int C2 = in_sizes[6];           // 256
    const int C5 = in_sizes[12];          // 10
    const int G  = out_size / (C2 + C5);  // 512
    const int NB = DIV_UP(N, 1024);

    const int* srcp = ei;
    const int* dstp = ei + E;

    // ---- workspace layout (256B-aligned carve-outs) ----
    uintptr_t p = (uintptr_t)d_ws;
    auto carve = [&](size_t bytes) {
        uintptr_t r = p;
        p += (bytes + 255) & ~(size_t)255;
        return (void*)r;
    };
    int* hist    = (int*)carve(sizeof(int) * N);
    int* cursor  = (int*)carve(sizeof(int) * N);      // MUST follow hist (joint zero-fill)
    int* row_off = (int*)carve(sizeof(int) * (N + 1));
    int* bounds  = (int*)carve(sizeof(int) * (G + 1));
    int* bsum    = (int*)carve(sizeof(int) * NB);
    int* boff    = (int*)carve(sizeof(int) * NB);
    int* csr_src = (int*)carve(sizeof(int) * E);
    float* csr_w = (float*)carve(sizeof(float) * E);
    float* dinv  = (float*)carve(sizeof(float) * N);
    float* wct   = (float*)carve(sizeof(float) * C2 * C5);
    float* bcv   = (float*)carve(sizeof(float) * C5);
    unsigned short* w1t = (unsigned short*)carve(sizeof(short) * F * C1);
    unsigned short* w2t = (unsigned short*)carve(sizeof(short) * C1 * C2);
    unsigned short* xb    = (unsigned short*)carve(sizeof(short) * (size_t)N * F);
    unsigned short* aggxb = (unsigned short*)carve(sizeof(short) * (size_t)N * F);
    unsigned short* h1b   = (unsigned short*)carve(sizeof(short) * (size_t)N * C1);
    unsigned short* t2b   = (unsigned short*)carve(sizeof(short) * (size_t)N * C2);
    unsigned short* h2b   = (unsigned short*)carve(sizeof(short) * (size_t)N * C2);

    float* out     = (float*)d_out;
    float* out_emb = out + (size_t)G * C5;

    // ---- CSR build + dinv + graph bounds + head-weight precompute ----
    int zspan = (int)(((sizeof(int) * N + 255) & ~(size_t)255) / 4) + N;  // hist..cursor
    k_zero_i<<<DIV_UP(zspan, 256), 256, 0, stream>>>(hist, zspan);
    k_hist<<<DIV_UP(E, 256), 256, 0, stream>>>(dstp, hist, E);
    k_scan_bsum<<<NB, 256, 0, stream>>>(hist, bsum, N);
    k_scan_boff<<<1, 1024, 0, stream>>>(bsum, boff, row_off, NB, N);
    k_scan_apply<<<NB, 256, 0, stream>>>(hist, boff, row_off, dinv, N);
    k_bin<<<DIV_UP(E, 256), 256, 0, stream>>>(srcp, dstp, row_off, cursor, dinv,
                                              csr_src, csr_w, E);
    k_bounds<<<DIV_UP(G + 1, 256), 256, 0, stream>>>(batch, bounds, N, G);
    k_wc<<<11, 256, 0, stream>>>(W3, W4, W5, b3, b4, b5, wct, bcv);

    // ---- fused conversions (x->bf16, W1^T, W2^T) ----
    int n4 = N * F / 4;
    int prep_total = n4 + F * C1 + C1 * C2;
    k_prep<<<DIV_UP(prep_total, 256), 256, 0, stream>>>(x, xb, n4,
                                                        W1, w1t, F, C1,
                                                        W2, w2t, C1, C2);

    // ---- layer 1: gather (bf16) -> MFMA GEMM + bias + leakyrelu -> h1 bf16 ----
    k_gather_b<128><<<DIV_UP(N, 16), 256, 0, stream>>>(
        xb, row_off, csr_src, csr_w, dinv, nullptr, aggxb, N);
    dim3 g1(C1 / 128, DIV_UP(N, 128));
    k_gemm_mfma<1, 1><<<g1, 256, 0, stream>>>(aggxb, w1t, b1, h1b, N, F, C1);

    // ---- layer 2: MFMA GEMM -> t2 bf16 -> gather (+b2) -> h2 bf16 ----
    dim3 g2(C2 / 128, DIV_UP(N, 128));
    k_gemm_mfma<1, 0><<<g2, 256, 0, stream>>>(h1b, w2t, nullptr, t2b, N, C1, C2);
    k_gather_b<256><<<DIV_UP(N, 8), 256, 0, stream>>>(
        t2b, row_off, csr_src, csr_w, dinv, b2, h2b, N);

    // ---- fused head + both segment_maxes ----
    k_head_segmax<<<G, 320, 0, stream>>>(h2b, wct, bcv, bounds, out, out_emb);
}

// Round 9
// 286.401 us; speedup vs baseline: 9.1776x; 1.0839x over previous
//
#include <hip/hip_runtime.h>
#include <math.h>

#define DIV_UP(a,b) (((a)+(b)-1)/(b))

typedef __attribute__((ext_vector_type(8))) short bf16x8;
typedef __attribute__((ext_vector_type(4))) float f32x4;

// fp32 -> bf16 round-to-nearest-even
__device__ inline unsigned short f2b(float x) {
    unsigned int u = __float_as_uint(x);
    u += 0x7fffu + ((u >> 16) & 1u);
    return (unsigned short)(u >> 16);
}

// 8 packed bf16 (uint4) -> 8 floats
__device__ inline void cvt8(uint4 v, float* a) {
    a[0] = __uint_as_float(v.x << 16); a[1] = __uint_as_float(v.x & 0xffff0000u);
    a[2] = __uint_as_float(v.y << 16); a[3] = __uint_as_float(v.y & 0xffff0000u);
    a[4] = __uint_as_float(v.z << 16); a[5] = __uint_as_float(v.z & 0xffff0000u);
    a[6] = __uint_as_float(v.w << 16); a[7] = __uint_as_float(v.w & 0xffff0000u);
}

// async global->LDS 16B
__device__ inline void gl16(void* lds, const void* g) {
    __builtin_amdgcn_global_load_lds(
        (const __attribute__((address_space(1))) void*)g,
        (__attribute__((address_space(3))) void*)lds, 16, 0, 0);
}

__global__ void k_zero_i(int* p, int n) {
    int i = blockIdx.x * blockDim.x + threadIdx.x;
    if (i < n) p[i] = 0;
}

__global__ void k_hist(const int* __restrict__ dst, int* __restrict__ hist, int E) {
    int i = blockIdx.x * blockDim.x + threadIdx.x;
    if (i < E) atomicAdd(&hist[dst[i]], 1);
}

// ---- hierarchical scan ----
__global__ __launch_bounds__(256) void k_scan_bsum(const int* __restrict__ hist,
                                                   int* __restrict__ bsum, int N) {
    __shared__ int red[256];
    int t = threadIdx.x;
    int base = blockIdx.x * 1024 + t * 4;
    int s = 0;
    if (base + 3 < N) {
        int4 v = *(const int4*)&hist[base];
        s = v.x + v.y + v.z + v.w;
    } else {
        for (int j = 0; j < 4; ++j) if (base + j < N) s += hist[base + j];
    }
    red[t] = s;
    __syncthreads();
    for (int off = 128; off >= 1; off >>= 1) {
        if (t < off) red[t] += red[t + off];
        __syncthreads();
    }
    if (t == 0) bsum[blockIdx.x] = red[0];
}

__global__ __launch_bounds__(1024) void k_scan_boff(const int* __restrict__ bsum,
        int* __restrict__ boff, int* __restrict__ row_off, int NB, int N) {
    __shared__ int s[1024];
    int t = threadIdx.x;
    int v = (t < NB) ? bsum[t] : 0;
    s[t] = v;
    __syncthreads();
    for (int off = 1; off < 1024; off <<= 1) {
        int u = (t >= off) ? s[t - off] : 0;
        __syncthreads();
        s[t] += u;
        __syncthreads();
    }
    if (t < NB) boff[t] = s[t] - v;
    if (t == NB - 1) row_off[N] = s[t];
}

// scan apply + dinv fused
__global__ __launch_bounds__(256) void k_scan_apply(const int* __restrict__ hist,
        const int* __restrict__ boff, int* __restrict__ row_off,
        float* __restrict__ dinv, int N) {
    __shared__ int s[256];
    int t = threadIdx.x;
    int base = blockIdx.x * 1024 + t * 4;
    int v[4];
    int loc = 0;
#pragma unroll
    for (int j = 0; j < 4; ++j) { v[j] = (base + j < N) ? hist[base + j] : 0; loc += v[j]; }
    s[t] = loc;
    __syncthreads();
    for (int off = 1; off < 256; off <<= 1) {
        int u = (t >= off) ? s[t - off] : 0;
        __syncthreads();
        s[t] += u;
        __syncthreads();
    }
    int run = boff[blockIdx.x] + s[t] - loc;
#pragma unroll
    for (int j = 0; j < 4; ++j) {
        if (base + j < N) {
            row_off[base + j] = run;
            dinv[base + j] = rsqrtf((float)(v[j] + 1));
        }
        run += v[j];
    }
}

__global__ void k_bin(const int* __restrict__ src, const int* __restrict__ dst,
                      const int* __restrict__ row_off, int* __restrict__ cursor,
                      const float* __restrict__ dinv,
                      int* __restrict__ csr_src, float* __restrict__ csr_w, int E) {
    int i = blockIdx.x * blockDim.x + threadIdx.x;
    if (i >= E) return;
    int d = dst[i], s = src[i];
    int pos = row_off[d] + atomicAdd(&cursor[d], 1);
    csr_src[pos] = s;
    csr_w[pos] = dinv[s] * dinv[d];
}

// fused preprocessing, block-range partitioned:
//   blocks [0,11):        head-weight collapse (WcT = (W3@W4@W5)^T, bc chain)
//   blocks [11,11+nb):    graph bounds binary search
//   blocks [11+nb, ...):  x->bf16, W1^T->bf16, W2^T->bf16
__global__ __launch_bounds__(256) void k_pre(
        const float* __restrict__ W3, const float* __restrict__ W4,
        const float* __restrict__ W5, const float* __restrict__ b3,
        const float* __restrict__ b4, const float* __restrict__ b5,
        float* __restrict__ WcT, float* __restrict__ bc,
        const int* __restrict__ batch, int* __restrict__ bounds, int N, int G, int nb,
        const float* __restrict__ x, unsigned short* __restrict__ xb, int n4,
        const float* __restrict__ W1, unsigned short* __restrict__ w1t, int K1, int N1,
        const float* __restrict__ W2, unsigned short* __restrict__ w2t, int K2, int N2) {
    int b = blockIdx.x;
    int t = threadIdx.x;
    if (b < 11) {
        int c = b;
        if (c < 10) {
            __shared__ float Tc[128];
            if (t < 128) {
                float s = 0.f;
#pragma unroll 8
                for (int k = 0; k < 32; ++k) s = fmaf(W4[t * 32 + k], W5[k * 10 + c], s);
                Tc[t] = s;
            }
            __syncthreads();
            float s = 0.f;
            const float* w3r = &W3[t * 128];
#pragma unroll 8
            for (int j = 0; j < 128; ++j) s = fmaf(w3r[j], Tc[j], s);
            WcT[c * 256 + t] = s;
        } else {
            __shared__ float v[32];
            if (t < 32) {
                float s = b4[t];
                for (int j = 0; j < 128; ++j) s = fmaf(b3[j], W4[j * 32 + t], s);
                v[t] = s;
            }
            __syncthreads();
            if (t < 10) {
                float s = b5[t];
                for (int k = 0; k < 32; ++k) s = fmaf(v[k], W5[k * 10 + t], s);
                bc[t] = s;
            }
        }
        return;
    }
    if (b < 11 + nb) {
        int g = (b - 11) * 256 + t;
        if (g > G) return;
        int lo = 0, hi = N;
        while (lo < hi) { int mid = (lo + hi) >> 1; if (batch[mid] < g) lo = mid + 1; else hi = mid; }
        bounds[g] = lo;
        return;
    }
    int i = (b - 11 - nb) * 256 + t;
    if (i < n4) {
        float4 v = ((const float4*)x)[i];
        ushort4 o;
        o.x = f2b(v.x); o.y = f2b(v.y); o.z = f2b(v.z); o.w = f2b(v.w);
        ((ushort4*)xb)[i] = o;
        return;
    }
    i -= n4;
    if (i < K1 * N1) {
        int k = i / N1, n = i % N1;
        w1t[(size_t)n * K1 + k] = f2b(W1[i]);
        return;
    }
    i -= K1 * N1;
    if (i < K2 * N2) {
        int k = i / N2, n = i % N2;
        w2t[(size_t)n * K2 + k] = f2b(W2[i]);
    }
}

// gather-aggregate over dst-CSR, bf16 in/out, ILP-4 edge loop.
template <int F>
__global__ __launch_bounds__(256) void k_gather_b(const unsigned short* __restrict__ H,
        const int* __restrict__ row_off, const int* __restrict__ csr_src,
        const float* __restrict__ csr_w, const float* __restrict__ dinv,
        const float* __restrict__ bias, unsigned short* __restrict__ outb, int N) {
    const int LPN = F / 8;
    const int NPB = 256 / LPN;
    int node = blockIdx.x * NPB + threadIdx.x / LPN;
    if (node >= N) return;
    int f = (threadIdx.x % LPN) * 8;
    const unsigned short* Hf = H + f;
    float sc = dinv[node]; sc *= sc;
    float a[8];
    cvt8(*(const uint4*)&Hf[(size_t)node * F], a);
#pragma unroll
    for (int j = 0; j < 8; ++j) a[j] *= sc;
    if (bias) {
#pragma unroll
        for (int j = 0; j < 8; ++j) a[j] += bias[f + j];
    }
    int e0 = row_off[node], e1 = row_off[node + 1];
    int e = e0;
    for (; e + 4 <= e1; e += 4) {
        int s0 = csr_src[e + 0], s1 = csr_src[e + 1];
        int s2 = csr_src[e + 2], s3 = csr_src[e + 3];
        uint4 v0 = *(const uint4*)&Hf[(size_t)s0 * F];
        uint4 v1 = *(const uint4*)&Hf[(size_t)s1 * F];
        uint4 v2 = *(const uint4*)&Hf[(size_t)s2 * F];
        uint4 v3 = *(const uint4*)&Hf[(size_t)s3 * F];
        float w0 = csr_w[e + 0], w1 = csr_w[e + 1];
        float w2 = csr_w[e + 2], w3 = csr_w[e + 3];
        float b0[8], b1[8], b2[8], b3[8];
        cvt8(v0, b0); cvt8(v1, b1); cvt8(v2, b2); cvt8(v3, b3);
#pragma unroll
        for (int j = 0; j < 8; ++j) {
            a[j] = fmaf(w0, b0[j], a[j]);
            a[j] = fmaf(w1, b1[j], a[j]);
            a[j] = fmaf(w2, b2[j], a[j]);
            a[j] = fmaf(w3, b3[j], a[j]);
        }
    }
    for (; e < e1; ++e) {
        int s = csr_src[e];
        float w = csr_w[e];
        float b[8];
        cvt8(*(const uint4*)&Hf[(size_t)s * F], b);
#pragma unroll
        for (int j = 0; j < 8; ++j) a[j] = fmaf(w, b[j], a[j]);
    }
    uint4 o;
    o.x = (unsigned)f2b(a[0]) | ((unsigned)f2b(a[1]) << 16);
    o.y = (unsigned)f2b(a[2]) | ((unsigned)f2b(a[3]) << 16);
    o.z = (unsigned)f2b(a[4]) | ((unsigned)f2b(a[5]) << 16);
    o.w = (unsigned)f2b(a[6]) | ((unsigned)f2b(a[7]) << 16);
    *(uint4*)&outb[(size_t)node * F + f] = o;
}

// bf16 MFMA GEMM, fat-N tile: 128x256 per block, 512 threads = 8 waves (2x4),
// each wave 64x64 via 4x4 grid of 16x16x32 MFMAs, BK=64, global_load_lds w16,
// XOR-swizzled LDS, operand-swap mfma (lane = row + 4 contiguous cols).
template <int OUT_BF16, int ACT>
__global__ __launch_bounds__(512) void k_gemm_mfma256(const unsigned short* __restrict__ A,
        const unsigned short* __restrict__ Bt, const float* __restrict__ bias,
        void* __restrict__ Cout, int M, int K, int NC) {
    __shared__ __align__(16) unsigned short As[128][64];   // 16 KB
    __shared__ __align__(16) unsigned short Bs[256][64];   // 32 KB
    int tid = threadIdx.x;
    int wave = tid >> 6, lane = tid & 63;
    int row0 = blockIdx.y * 128, col0 = blockIdx.x * 256;
    int wr = (wave >> 2) * 64, wc = (wave & 3) * 64;
    f32x4 acc[4][4] = {};
    int lr = lane & 15;
    int lg = lane >> 4;
    int sw = ((lane & 7) ^ (lane >> 3)) << 3;
    int ch0 = (lg ^ (lr & 7)) << 3;
    int ch1 = ch0 ^ (4 << 3);

    for (int k0 = 0; k0 < K; k0 += 64) {
        // stage A: 2 rounds x (8 waves x 8 rows), B: 4 rounds
#pragma unroll
        for (int c = 0; c < 2; ++c) {
            int rl = c * 64 + wave * 8 + (lane >> 3);
            int gr = min(row0 + rl, M - 1);
            gl16(&As[c * 64 + wave * 8][0], &A[(size_t)gr * K + k0 + sw]);
        }
#pragma unroll
        for (int c = 0; c < 4; ++c) {
            int rl = c * 64 + wave * 8 + (lane >> 3);
            gl16(&Bs[c * 64 + wave * 8][0], &Bt[(size_t)(col0 + rl) * K + k0 + sw]);
        }
        __syncthreads();
        bf16x8 af[2][4], bv[2][4];
#pragma unroll
        for (int i = 0; i < 4; ++i) {
            int ra = wr + i * 16 + lr;
            int rb = wc + i * 16 + lr;
            af[0][i] = *(const bf16x8*)&As[ra][ch0];
            af[1][i] = *(const bf16x8*)&As[ra][ch1];
            bv[0][i] = *(const bf16x8*)&Bs[rb][ch0];
            bv[1][i] = *(const bf16x8*)&Bs[rb][ch1];
        }
#pragma unroll
        for (int s = 0; s < 2; ++s)
#pragma unroll
            for (int i = 0; i < 4; ++i)
#pragma unroll
                for (int j = 0; j < 4; ++j)
                    acc[i][j] = __builtin_amdgcn_mfma_f32_16x16x32_bf16(bv[s][j], af[s][i], acc[i][j], 0, 0, 0);
        __syncthreads();
    }

    int q4 = lg * 4;
    float4 bb[4];
#pragma unroll
    for (int j = 0; j < 4; ++j)
        bb[j] = bias ? *(const float4*)&bias[col0 + wc + j * 16 + q4]
                     : make_float4(0.f, 0.f, 0.f, 0.f);
#pragma unroll
    for (int i = 0; i < 4; ++i) {
        int row = row0 + wr + i * 16 + lr;
        if (row >= M) continue;
#pragma unroll
        for (int j = 0; j < 4; ++j) {
            int c0 = col0 + wc + j * 16 + q4;
            float4 v;
            v.x = acc[i][j][0] + bb[j].x;
            v.y = acc[i][j][1] + bb[j].y;
            v.z = acc[i][j][2] + bb[j].z;
            v.w = acc[i][j][3] + bb[j].w;
            if (ACT) {
                v.x = (v.x >= 0.f) ? v.x : 0.01f * v.x;
                v.y = (v.y >= 0.f) ? v.y : 0.01f * v.y;
                v.z = (v.z >= 0.f) ? v.z : 0.01f * v.z;
                v.w = (v.w >= 0.f) ? v.w : 0.01f * v.w;
            }
            if (OUT_BF16) {
                uint2 o;
                o.x = (unsigned)f2b(v.x) | ((unsigned)f2b(v.y) << 16);
                o.y = (unsigned)f2b(v.z) | ((unsigned)f2b(v.w) << 16);
                *(uint2*)&((unsigned short*)Cout)[(size_t)row * NC + c0] = o;
            } else {
                *(float4*)&((float*)Cout)[(size_t)row * NC + c0] = v;
            }
        }
    }
}

// fused per-graph output: phase A = head (h2 @ Wc + bc, max over rows -> out[g,:10]);
// phase B = feature-wise segment_max of h2 -> out_emb[g,:256].
__global__ __launch_bounds__(320) void k_head_segmax(const unsigned short* __restrict__ H,
        const float* __restrict__ WcT, const float* __restrict__ bc,
        const int* __restrict__ bounds, float* __restrict__ out,
        float* __restrict__ out_emb) {
    __shared__ __align__(16) float Ws[10][260];
    __shared__ float bs[10];
    __shared__ float red[320];
    int t = threadIdx.x;
    for (int i = t; i < 2560; i += 320) Ws[i / 256][i % 256] = WcT[i];
    if (t < 10) bs[t] = bc[t];
    __syncthreads();
    int g = blockIdx.x;
    int s = bounds[g], e = bounds[g + 1];
    int col = t % 10, rs = t / 10;
    float m = -INFINITY;
    for (int r = s + rs; r < e; r += 32) {
        const unsigned short* hr = &H[(size_t)r * 256];
        float acc = bs[col];
#pragma unroll 4
        for (int k = 0; k < 256; k += 8) {
            float h[8];
            cvt8(*(const uint4*)&hr[k], h);
            float4 wa = *(const float4*)&Ws[col][k];
            float4 wb = *(const float4*)&Ws[col][k + 4];
            acc = fmaf(h[0], wa.x, acc);
            acc = fmaf(h[1], wa.y, acc);
            acc = fmaf(h[2], wa.z, acc);
            acc = fmaf(h[3], wa.w, acc);
            acc = fmaf(h[4], wb.x, acc);
            acc = fmaf(h[5], wb.y, acc);
            acc = fmaf(h[6], wb.z, acc);
            acc = fmaf(h[7], wb.w, acc);
        }
        m = fmaxf(m, acc);
    }
    red[t] = m;
    __syncthreads();
    for (int step = 16; step >= 1; step >>= 1) {
        if (rs < step) red[rs * 10 + col] = fmaxf(red[rs * 10 + col], red[(rs + step) * 10 + col]);
        __syncthreads();
    }
    if (rs == 0) out[(size_t)g * 10 + col] = red[col];
    if (t < 256) {
        float mm = -INFINITY;
        for (int r = s; r < e; ++r)
            mm = fmaxf(mm, __uint_as_float(((unsigned)H[(size_t)r * 256 + t]) << 16));
        out_emb[(size_t)g * 256 + t] = mm;
    }
}

extern "C" void kernel_launch(void* const* d_in, const int* in_sizes, int n_in,
                              void* d_out, int out_size, void* d_ws, size_t ws_size,
                              hipStream_t stream) {
    const float* x  = (const float*)d_in[0];
    const int* ei   = (const int*)d_in[1];
    const int* batch= (const int*)d_in[2];
    const float* W1 = (const float*)d_in[3];
    const float* b1 = (const float*)d_in[4];
    const float* W2 = (const float*)d_in[5];
    const float* b2 = (const float*)d_in[6];
    const float* W3 = (const float*)d_in[7];
    const float* b3 = (const float*)d_in[8];
    const float* W4 = (const float*)d_in[9];
    const float* b4 = (const float*)d_in[10];
    const float* W5 = (const float*)d_in[11];
    const float* b5 = (const float*)d_in[12];

    const int N  = in_sizes[2];           // 50000
    const int F  = in_sizes[0] / N;       // 128
    const int E  = in_sizes[1] / 2;       // 400000
    const int C1 = in_sizes[4];           // 512
    const int C2 = in_sizes[6];           // 256
    const int C5 = in_sizes[12];          // 10
    const int G  = out_size / (C2 + C5);  // 512
    const int NB = DIV_UP(N, 1024);

    const int* srcp = ei;
    const int* dstp = ei + E;

    // ---- workspace layout (256B-aligned carve-outs) ----
    uintptr_t p = (uintptr_t)d_ws;
    auto carve = [&](size_t bytes) {
        uintptr_t r = p;
        p += (bytes + 255) & ~(size_t)255;
        return (void*)r;
    };
    int* hist    = (int*)carve(sizeof(int) * N);
    int* cursor  = (int*)carve(sizeof(int) * N);      // MUST follow hist (joint zero-fill)
    int* row_off = (int*)carve(sizeof(int) * (N + 1));
    int* bounds  = (int*)carve(sizeof(int) * (G + 1));
    int* bsum    = (int*)carve(sizeof(int) * NB);
    int* boff    = (int*)carve(sizeof(int) * NB);
    int* csr_src = (int*)carve(sizeof(int) * E);
    float* csr_w = (float*)carve(sizeof(float) * E);
    float* dinv  = (float*)carve(sizeof(float) * N);
    float* wct   = (float*)carve(sizeof(float) * C2 * C5);
    float* bcv   = (float*)carve(sizeof(float) * C5);
    unsigned short* w1t = (unsigned short*)carve(sizeof(short) * F * C1);
    unsigned short* w2t = (unsigned short*)carve(sizeof(short) * C1 * C2);
    unsigned short* xb    = (unsigned short*)carve(sizeof(short) * (size_t)N * F);
    unsigned short* aggxb = (unsigned short*)carve(sizeof(short) * (size_t)N * F);
    unsigned short* h1b   = (unsigned short*)carve(sizeof(short) * (size_t)N * C1);
    unsigned short* t2b   = (unsigned short*)carve(sizeof(short) * (size_t)N * C2);
    unsigned short* h2b   = (unsigned short*)carve(sizeof(short) * (size_t)N * C2);

    float* out     = (float*)d_out;
    float* out_emb = out + (size_t)G * C5;

    // ---- CSR build + fused preprocessing ----
    int zspan = (int)(((sizeof(int) * N + 255) & ~(size_t)255) / 4) + N;  // hist..cursor
    k_zero_i<<<DIV_UP(zspan, 256), 256, 0, stream>>>(hist, zspan);
    k_hist<<<DIV_UP(E, 256), 256, 0, stream>>>(dstp, hist, E);
    k_scan_bsum<<<NB, 256, 0, stream>>>(hist, bsum, N);
    k_scan_boff<<<1, 1024, 0, stream>>>(bsum, boff, row_off, NB, N);
    k_scan_apply<<<NB, 256, 0, stream>>>(hist, boff, row_off, dinv, N);
    k_bin<<<DIV_UP(E, 256), 256, 0, stream>>>(srcp, dstp, row_off, cursor, dinv,
                                              csr_src, csr_w, E);

    int n4 = N * F / 4;
    int nb_bounds = DIV_UP(G + 1, 256);
    int prep_total = n4 + F * C1 + C1 * C2;
    int pre_blocks = 11 + nb_bounds + DIV_UP(prep_total, 256);
    k_pre<<<pre_blocks, 256, 0, stream>>>(W3, W4, W5, b3, b4, b5, wct, bcv,
                                          batch, bounds, N, G, nb_bounds,
                                          x, xb, n4, W1, w1t, F, C1, W2, w2t, C1, C2);

    // ---- layer 1: gather (bf16) -> fat-N MFMA GEMM + bias + leakyrelu -> h1 bf16 ----
    k_gather_b<128><<<DIV_UP(N, 16), 256, 0, stream>>>(
        xb, row_off, csr_src, csr_w, dinv, nullptr, aggxb, N);
    dim3 g1(C1 / 256, DIV_UP(N, 128));
    k_gemm_mfma256<1, 1><<<g1, 512, 0, stream>>>(aggxb, w1t, b1, h1b, N, F, C1);

    // ---- layer 2: fat-N MFMA GEMM -> t2 bf16 -> gather (+b2) -> h2 bf16 ----
    dim3 g2(C2 / 256, DIV_UP(N, 128));
    k_gemm_mfma256<1, 0><<<g2, 512, 0, stream>>>(h1b, w2t, nullptr, t2b, N, C1, C2);
    k_gather_b<256><<<DIV_UP(N, 8), 256, 0, stream>>>(
        t2b, row_off, csr_src, csr_w, dinv, b2, h2b, N);

    // ---- fused head + both segment_maxes ----
    k_head_segmax<<<G, 320, 0, stream>>>(h2b, wct, bcv, bounds, out, out_emb);
}